// Round 5
// baseline (288.167 us; speedup 1.0000x reference)
//
#include <hip/hip_runtime.h>

// ---------------- workspace layout (float offsets) ----------------
#define WS_WC     ((size_t)0)        //  8192  Wc (1024x8)
#define WS_BCQ    ((size_t)8192)     //  1024  bc + pos_q[0]
#define WS_WQP    ((size_t)9216)     //  4096  Wq' (512x8)
#define WS_BQP    ((size_t)13312)    //   512  bq'
#define WS_U      ((size_t)13824)    //    64  u[h][8]   (bk fold)
#define WS_V      ((size_t)13888)    //     8  v[h]
#define WS_G      ((size_t)14336)    // 65536  G (8x1024x8)
#define WS_G0     ((size_t)79872)    //  8192  g0 (8x1024)
#define WS_POST   ((size_t)88064)    // 212992 pos_kv^T (1024x208, zero-padded)
#define WS_M0     ((size_t)302080)   //  2048  m0 (256x8)
#define WS_AJ     ((size_t)304128)   // 14976  AJ (8h x 9 x 208): j<8 = G-fold, j=8 = g0-fold
#define WS_WFM    ((size_t)2008064)  // 425984 fm-weights (256x8x208)
#define WS_WPOS   ((size_t)2434048)  // 425984 pos-weights (256x8x208)
#define WS_S      ((size_t)2860032)  // 2097152 s (8x256x1024)
#define WS_OVP    ((size_t)4957184)  // 1048576 ov partials (8x256x512)
#define WS_O1P    ((size_t)6005760)  // 1048576 out1 partials (4x256x1024)
#define WS_OV     ((size_t)7259136)  // 131072 reduced ov (256x512)
#define WS_ATT8   ((size_t)7390208)  // 3407872 att partials (256x8x8x208)
// total 10798080 floats = 43.2 MB (ws is ~800 MB per fill counters)
#define WS_M4     WS_S    // scratch before kb writes WS_S
#define WS_PP     WS_OVP  // scratch (4ci x 8h x 9) before kv_ov writes OVP

// ---------------- KP1a: small chain stages + pos_kv transpose ----------------
__global__ __launch_bounds__(256) void kp1a_chain_post(
    const float* __restrict__ w1, const float* __restrict__ b1,
    const float* __restrict__ w2, const float* __restrict__ b2,
    const float* __restrict__ w3, const float* __restrict__ b3,
    const float* __restrict__ w4, const float* __restrict__ b4,
    const float* __restrict__ pos_kv, float* __restrict__ ws)
{
  __shared__ float shm[12864];   // 51.5 KB; union of both paths
  const int t = threadIdx.x;
  if (blockIdx.x == 0) {
    float* wt  = shm;            // W3 [128][65]=8320 / W4 tile [64][129]=8256
    float* M2s = shm + 8320;     // 512
    float* C2s = shm + 8832;     // 64
    float* M3s = shm + 8896;     // 1024
    float* C3s = shm + 9920;     // 128
    float* M4s = shm + 10048;    // 2048
    float* C4s = shm + 12096;    // 256

    for (int idx = t; idx < 2048; idx += 256) {        // W3 -> LDS
      const float4 v = ((const float4*)w3)[idx];
      const int r = idx >> 4, i = (idx & 15) * 4;
      float* d = &wt[r * 65 + i];
      d[0] = v.x; d[1] = v.y; d[2] = v.z; d[3] = v.w;
    }
    for (int idx = t; idx < 512; idx += 256) {
      const int o = idx >> 3, j = idx & 7;
      float a = 0.f;
      for (int i = 0; i < 32; ++i) a += w2[o*32+i] * w1[i*8+j];
      M2s[idx] = a;
    }
    if (t < 64) {
      float a = b2[t];
      for (int i = 0; i < 32; ++i) a += w2[t*32+i] * b1[i];
      C2s[t] = a;
    }
    __syncthreads();
    for (int idx = t; idx < 1024; idx += 256) {
      const int o = idx >> 3, j = idx & 7;
      const float* wr = &wt[o * 65];
      float a = 0.f;
      for (int i = 0; i < 64; ++i) a += wr[i] * M2s[i*8+j];
      M3s[idx] = a;
    }
    if (t < 128) {
      const float* wr = &wt[t * 65];
      float a = b3[t];
      for (int i = 0; i < 64; ++i) a += wr[i] * C2s[i];
      C3s[t] = a;
    }
    __syncthreads();
    for (int oc = 0; oc < 4; ++oc) {
      for (int idx = t; idx < 2048; idx += 256) {
        const float4 v = ((const float4*)w4)[oc*2048 + idx];
        const int r = idx >> 5, i = (idx & 31) * 4;
        float* d = &wt[r * 129 + i];
        d[0] = v.x; d[1] = v.y; d[2] = v.z; d[3] = v.w;
      }
      __syncthreads();
      for (int idx = t; idx < 512; idx += 256) {
        const int r = idx >> 3, j = idx & 7;
        const float* wr = &wt[r * 129];
        float a = 0.f;
        for (int i = 0; i < 128; ++i) a += wr[i] * M3s[i*8+j];
        M4s[(oc*64 + r)*8 + j] = a;
      }
      if (t < 64) {
        const float* wr = &wt[t * 129];
        float a = b4[oc*64 + t];
        for (int i = 0; i < 128; ++i) a += wr[i] * C3s[i];
        C4s[oc*64 + t] = a;
      }
      __syncthreads();
    }
    for (int idx = t; idx < 2048; idx += 256) ws[WS_M4 + idx] = M4s[idx];
    ws[WS_M4 + 2048 + t] = C4s[t];
  } else {
    const int c0 = (blockIdx.x - 1) * 64;
    const int c = t & 63, nb = t >> 6;
    for (int n = nb; n < 197; n += 4)
      shm[c*201 + n] = pos_kv[(size_t)n*1024 + c0 + c];
    __syncthreads();
    for (int idx = t; idx < 64*208; idx += 256) {
      int cc = idx / 208, n = idx - cc*208;
      ws[WS_POST + (size_t)(c0+cc)*208 + n] = (n < 197) ? shm[cc*201+n] : 0.f;
    }
  }
}

// ---------------- KP1b: W5 fold (1024x8), 32 rows/block ----------------
__global__ __launch_bounds__(256) void kp1b_w5fold(
    const float* __restrict__ w5, const float* __restrict__ b5,
    const float* __restrict__ pos_q, float* __restrict__ ws)
{
  __shared__ float wt[32 * 257];
  __shared__ float M4s[2304];
  const int t = threadIdx.x, ob = blockIdx.x;
  const int o0 = ob * 32;
  for (int idx = t; idx < 2304; idx += 256) M4s[idx] = ws[WS_M4 + idx];
  for (int idx = t; idx < 2048; idx += 256) {
    const float4 v = ((const float4*)w5)[(size_t)ob*2048 + idx];
    const int r = idx >> 6, i = (idx & 63) * 4;
    float* d = &wt[r * 257 + i];
    d[0] = v.x; d[1] = v.y; d[2] = v.z; d[3] = v.w;
  }
  __syncthreads();
  const int r = t >> 3, j = t & 7;
  const float* wr = &wt[r * 257];
  float a = 0.f;
  for (int i = 0; i < 256; ++i) a += wr[i] * M4s[i*8 + j];
  ws[WS_WC + (size_t)(o0 + r)*8 + j] = a;
  if (t < 32) {
    const float* wb = &wt[t * 257];
    float a2 = b5[o0 + t];
    for (int i = 0; i < 256; ++i) a2 += wb[i] * M4s[2048 + i];
    ws[WS_BCQ + o0 + t] = a2 + pos_q[o0 + t];
  }
}

// ---------------- KP2a: Wq' = wq @ Wc, bq' (wave per output row) ----------------
__global__ __launch_bounds__(256) void kp2a_qproj(
    const float* __restrict__ wq, const float* __restrict__ bq,
    float* __restrict__ ws)
{
  const int t = threadIdx.x;
  const int w = t >> 6, l = t & 63;
  const int o = blockIdx.x * 4 + w;
  const float* wqr = wq + (size_t)o * 1024;
  float acc[8] = {0,0,0,0,0,0,0,0};
  float accb = 0.f;
  for (int k = 0; k < 16; ++k) {
    const int c = l + 64*k;
    const float wv_ = wqr[c];
    const float4 a  = *(const float4*)&ws[WS_WC + (size_t)c*8];
    const float4 b2 = *(const float4*)&ws[WS_WC + (size_t)c*8 + 4];
    acc[0] += wv_*a.x;  acc[1] += wv_*a.y;  acc[2] += wv_*a.z;  acc[3] += wv_*a.w;
    acc[4] += wv_*b2.x; acc[5] += wv_*b2.y; acc[6] += wv_*b2.z; acc[7] += wv_*b2.w;
    accb += wv_ * ws[WS_BCQ + c];
  }
  for (int off = 32; off >= 1; off >>= 1) {
#pragma unroll
    for (int j = 0; j < 8; ++j) acc[j] += __shfl_xor(acc[j], off);
    accb += __shfl_xor(accb, off);
  }
  if (l == 0) {
#pragma unroll
    for (int j = 0; j < 8; ++j) ws[WS_WQP + (size_t)o*8 + j] = acc[j];
    ws[WS_BQP + o] = accb + bq[o];
  }
}

// ---------------- KP2b: G / g0 (c split over 4 blocks per head) + folds ------
__global__ __launch_bounds__(256) void kp2b_gfold(
    const float* __restrict__ wk, const float* __restrict__ bk,
    const float* __restrict__ pos_kv, float* __restrict__ ws)
{
  const int ci = blockIdx.x, h = blockIdx.y, t = threadIdx.x;
  __shared__ float WQs[512];
  __shared__ float BQs[64];
  __shared__ float red2[9 * 256];
  for (int idx = t; idx < 512; idx += 256) WQs[idx] = ws[WS_WQP + (size_t)h*512 + idx];
  if (t < 64) BQs[t] = ws[WS_BQP + h*64 + t];
  __syncthreads();

  const int c = ci*256 + t;
  float accG[8] = {0,0,0,0,0,0,0,0};
  float accg0 = 0.f;
  const float* wkc = wk + (size_t)h*64*1024 + c;
  for (int d = 0; d < 64; ++d) {
    const float wkv = wkc[(size_t)d*1024];
    const float4 qa = *(const float4*)&WQs[d*8];
    const float4 qb = *(const float4*)&WQs[d*8+4];
    accG[0] += wkv*qa.x; accG[1] += wkv*qa.y; accG[2] += wkv*qa.z; accG[3] += wkv*qa.w;
    accG[4] += wkv*qb.x; accG[5] += wkv*qb.y; accG[6] += wkv*qb.z; accG[7] += wkv*qb.w;
    accg0 += wkv * BQs[d];
  }
  *(float4*)&ws[WS_G + ((size_t)h*1024 + c)*8 + 0] = make_float4(accG[0],accG[1],accG[2],accG[3]);
  *(float4*)&ws[WS_G + ((size_t)h*1024 + c)*8 + 4] = make_float4(accG[4],accG[5],accG[6],accG[7]);
  ws[WS_G0 + (size_t)h*1024 + c] = accg0;

  // pos0 fold partials (qk . pos_kv[0])
  const float z0 = pos_kv[c];
#pragma unroll
  for (int j = 0; j < 8; ++j) red2[j*256 + t] = accG[j]*z0;
  red2[8*256 + t] = accg0*z0;
  __syncthreads();
  for (int s2 = 128; s2 >= 1; s2 >>= 1) {
    if (t < s2) {
#pragma unroll
      for (int j = 0; j < 9; ++j) red2[j*256 + t] += red2[j*256 + t + s2];
    }
    __syncthreads();
  }
  if (t == 0) {
    float* pp = &ws[WS_PP + ((size_t)ci*8 + h)*9];
#pragma unroll
    for (int j = 0; j < 9; ++j) pp[j] = red2[j*256];
  }

  if (ci == 0) {
    __syncthreads();
    const float bkv = (t < 64) ? bk[h*64 + t] : 0.f;
#pragma unroll
    for (int j = 0; j < 8; ++j)
      red2[j*256 + t] = (t < 64) ? bkv * WQs[t*8 + j] : 0.f;
    red2[8*256 + t] = (t < 64) ? bkv * BQs[t] : 0.f;
    __syncthreads();
    for (int s2 = 128; s2 >= 1; s2 >>= 1) {
      if (t < s2) {
#pragma unroll
        for (int j = 0; j < 9; ++j) red2[j*256 + t] += red2[j*256 + t + s2];
      }
      __syncthreads();
    }
    if (t == 0) {
#pragma unroll
      for (int j = 0; j < 8; ++j) ws[WS_U + h*8 + j] = red2[j*256];
      ws[WS_V + h] = red2[8*256];
    }
  }
}

// ---------------- KAJ: fold G/g0 against POST -> AJ[h][9][208] ----------------
// AJ[h][j][p] = sum_c G[h][c][j]*POST[c][p]  (j<8);  AJ[h][8][p] uses g0.
__global__ __launch_bounds__(256) void kaj_pfold(float* __restrict__ ws)
{
  const int blk = blockIdx.x, t = threadIdx.x;   // 72 blocks
  if (t >= 208) return;
  const int h = blk / 9, j = blk - h*9;
  float acc = 0.f;
  if (t < 196) {
    if (j < 8) {
      const float* gp = &ws[WS_G + (size_t)h*1024*8 + j];
      const float* pp = &ws[WS_POST + t];
      float a0=0.f,a1=0.f,a2=0.f,a3=0.f;
      for (int c = 0; c < 1024; c += 4) {
        a0 += gp[(size_t)(c+0)*8] * pp[(size_t)(c+0)*208];
        a1 += gp[(size_t)(c+1)*8] * pp[(size_t)(c+1)*208];
        a2 += gp[(size_t)(c+2)*8] * pp[(size_t)(c+2)*208];
        a3 += gp[(size_t)(c+3)*8] * pp[(size_t)(c+3)*208];
      }
      acc = (a0+a1)+(a2+a3);
    } else {
      const float* gp = &ws[WS_G0 + (size_t)h*1024];
      const float* pp = &ws[WS_POST + t];
      float a0=0.f,a1=0.f,a2=0.f,a3=0.f;
      for (int c = 0; c < 1024; c += 4) {
        a0 += gp[c+0] * pp[(size_t)(c+0)*208];
        a1 += gp[c+1] * pp[(size_t)(c+1)*208];
        a2 += gp[c+2] * pp[(size_t)(c+2)*208];
        a3 += gp[c+3] * pp[(size_t)(c+3)*208];
      }
      acc = (a0+a1)+(a2+a3);
    }
  }
  ws[WS_AJ + ((size_t)h*9 + j)*208 + t] = acc;
}

// ---------------- KA: att raw dots over fm only (b, 128-c chunk) --------------
__global__ __launch_bounds__(256) void ka_att(
    const float* __restrict__ fm, const float* __restrict__ lmap,
    float* __restrict__ ws)
{
  const int ci = blockIdx.x, b = blockIdx.y, t = threadIdx.x;
  __shared__ float qk[128 * 8];
  __shared__ float m0s[8];
  {
    const int ch = t >> 5, lp = t & 31;
    float s = 0.f;
    for (int p = lp; p < 196; p += 32) s += lmap[((size_t)b*8 + ch)*196 + p];
    for (int off = 16; off >= 1; off >>= 1) s += __shfl_xor(s, off);
    if (lp == 0) m0s[ch] = s * (1.f/196.f);
  }
  __syncthreads();
  float m0r[8];
#pragma unroll
  for (int j = 0; j < 8; ++j) m0r[j] = m0s[j];
  const int c0 = ci * 128;
  if (t < 128) {
    const int c = c0 + t;
#pragma unroll
    for (int h = 0; h < 8; ++h) {
      const float* gr = &ws[WS_G + ((size_t)h*1024 + c)*8];
      const float4 ga = *(const float4*)gr;
      const float4 gb = *(const float4*)(gr + 4);
      qk[t*8 + h] = ws[WS_G0 + (size_t)h*1024 + c]
                  + ga.x*m0r[0] + ga.y*m0r[1] + ga.z*m0r[2] + ga.w*m0r[3]
                  + gb.x*m0r[4] + gb.y*m0r[5] + gb.z*m0r[6] + gb.w*m0r[7];
    }
  }
  if (ci == 0 && t < 8) ws[WS_M0 + (size_t)b*8 + t] = m0s[t];
  __syncthreads();
  if (t < 98) {
    float a0[8] = {0,0,0,0,0,0,0,0};
    float a1[8] = {0,0,0,0,0,0,0,0};
    const float* fmp = fm + ((size_t)b*1024 + c0)*196 + 2*t;
    for (int cc = 0; cc < 128; ++cc) {
      const float2 f = *(const float2*)&fmp[(size_t)cc*196];
      const float4 qa = *(const float4*)&qk[cc*8];
      const float4 qb = *(const float4*)&qk[cc*8 + 4];
      a0[0] += qa.x*f.x; a1[0] += qa.x*f.y;
      a0[1] += qa.y*f.x; a1[1] += qa.y*f.y;
      a0[2] += qa.z*f.x; a1[2] += qa.z*f.y;
      a0[3] += qa.w*f.x; a1[3] += qa.w*f.y;
      a0[4] += qb.x*f.x; a1[4] += qb.x*f.y;
      a0[5] += qb.y*f.x; a1[5] += qb.y*f.y;
      a0[6] += qb.z*f.x; a1[6] += qb.z*f.y;
      a0[7] += qb.w*f.x; a1[7] += qb.w*f.y;
    }
    float* ap = &ws[WS_ATT8 + (((size_t)b*8 + ci)*8)*208 + 2*t];
#pragma unroll
    for (int h = 0; h < 8; ++h)
      *(float2*)&ap[h*208] = make_float2(a0[h], a1[h]);
  }
}

// ---------------- KSM: softmax (fm partials + folded pos term) ----------------
__global__ __launch_bounds__(256) void ksm_softmax(float* __restrict__ ws)
{
  const int b = blockIdx.x, t = threadIdx.x;
  __shared__ float wredA[32], wredB[32], wredC[32];
  const int wv_ = t >> 6;
  float m0r[8];
#pragma unroll
  for (int j = 0; j < 8; ++j) m0r[j] = ws[WS_M0 + (size_t)b*8 + j];
  float qbk[8], qs0[8];
#pragma unroll
  for (int h = 0; h < 8; ++h) {
    float s1 = ws[WS_V + h];
#pragma unroll
    for (int j = 0; j < 8; ++j) s1 += ws[WS_U + h*8 + j] * m0r[j];
    qbk[h] = s1;
    float s2 = 0.f;
    for (int ci = 0; ci < 4; ++ci) {
      const float* pp = &ws[WS_PP + ((size_t)ci*8 + h)*9];
      float v = pp[8];
#pragma unroll
      for (int j = 0; j < 8; ++j) v += pp[j]*m0r[j];
      s2 += v;
    }
    qs0[h] = s2;
  }
  // fm-only partial sums
  float a[8] = {0,0,0,0,0,0,0,0};
  if (t < 196) {
#pragma unroll
    for (int h = 0; h < 8; ++h) {
      float s = 0.f;
      for (int ci = 0; ci < 8; ++ci)
        s += ws[WS_ATT8 + (((size_t)b*8 + ci)*8 + h)*208 + t];
      a[h] = s;
    }
  }
  // S1 = sum over pixels (wave shuffle + cross-wave)
  {
    float r[8];
#pragma unroll
    for (int h = 0; h < 8; ++h) r[h] = a[h];
    for (int off = 32; off >= 1; off >>= 1) {
#pragma unroll
      for (int h = 0; h < 8; ++h) r[h] += __shfl_xor(r[h], off);
    }
    if ((t & 63) == 0) {
#pragma unroll
      for (int h = 0; h < 8; ++h) wredA[wv_*8 + h] = r[h];
    }
  }
  // pos term per pixel
  float pa[8];
#pragma unroll
  for (int h = 0; h < 8; ++h) pa[h] = 0.f;
  if (t < 196) {
#pragma unroll
    for (int h = 0; h < 8; ++h) {
      const float* aj = &ws[WS_AJ + (size_t)h*9*208];
      float v = aj[8*208 + t];
#pragma unroll
      for (int j = 0; j < 8; ++j) v += aj[j*208 + t]*m0r[j];
      pa[h] = v;
    }
  }
  __syncthreads();
  float fa[8], fa0[8];
#pragma unroll
  for (int h = 0; h < 8; ++h) {
    const float S1 = wredA[h] + wredA[8+h] + wredA[16+h] + wredA[24+h];
    fa[h]  = (a[h] + pa[h] + qbk[h]) * 0.125f;
    fa0[h] = (S1*(1.f/196.f) + qs0[h] + qbk[h]) * 0.125f;
  }
  // max
  {
    float r[8];
#pragma unroll
    for (int h = 0; h < 8; ++h) r[h] = (t < 196) ? fa[h] : -3.0e38f;
    for (int off = 32; off >= 1; off >>= 1) {
#pragma unroll
      for (int h = 0; h < 8; ++h) r[h] = fmaxf(r[h], __shfl_xor(r[h], off));
    }
    if ((t & 63) == 0) {
#pragma unroll
      for (int h = 0; h < 8; ++h) wredB[wv_*8 + h] = r[h];
    }
  }
  __syncthreads();
  float mh[8];
#pragma unroll
  for (int h = 0; h < 8; ++h)
    mh[h] = fmaxf(fmaxf(fmaxf(wredB[h], wredB[8+h]), fmaxf(wredB[16+h], wredB[24+h])), fa0[h]);
  float eh[8], e0[8];
#pragma unroll
  for (int h = 0; h < 8; ++h) {
    eh[h] = (t < 196) ? __expf(fa[h] - mh[h]) : 0.f;
    e0[h] = __expf(fa0[h] - mh[h]);
  }
  // sum of exps
  {
    float r[8];
#pragma unroll
    for (int h = 0; h < 8; ++h) r[h] = eh[h];
    for (int off = 32; off >= 1; off >>= 1) {
#pragma unroll
      for (int h = 0; h < 8; ++h) r[h] += __shfl_xor(r[h], off);
    }
    if ((t & 63) == 0) {
#pragma unroll
      for (int h = 0; h < 8; ++h) wredC[wv_*8 + h] = r[h];
    }
  }
  __syncthreads();
#pragma unroll
  for (int h = 0; h < 8; ++h) {
    const float lh  = wredC[h] + wredC[8+h] + wredC[16+h] + wredC[24+h] + e0[h];
    const float inv = 1.f / lh;
    const float w0  = e0[h] * inv;
    float* wfm = &ws[WS_WFM  + ((size_t)b*8 + h)*208];
    float* wpo = &ws[WS_WPOS + ((size_t)b*8 + h)*208];
    if (t < 196) {
      wfm[t]   = eh[h]*inv + w0*(1.f/196.f);
      wpo[t+1] = eh[h]*inv;
    } else if (t < 208) {
      wfm[t] = 0.f;
      if (t == 196) wpo[0] = w0;
      else          wpo[t] = 0.f;
    }
  }
}

// ---------------- KB-FM: fm weighted sums (swizzled LDS) ----------------
__global__ __launch_bounds__(256) void kb_fm(
    const float* __restrict__ fm, float* __restrict__ ws)
{
  __shared__ float fms[64 * 224];   // 56 float4 slots/row, slot XOR (c&7)
  __shared__ float wfs[1664];       // wfm[b] (8x208)
  const int cj = blockIdx.x, b = blockIdx.y, t = threadIdx.x;
  const int c0 = cj * 64;
  const float4* src = (const float4*)(fm + ((size_t)b*1024 + c0)*196);
  for (int idx = t; idx < 3136; idx += 256) {
    const float4 v = src[idx];
    const int c = idx / 49, q = idx - c*49;
    *(float4*)&fms[c*224 + ((q ^ (c & 7)) << 2)] = v;
  }
  const float4* wsrc = (const float4*)&ws[WS_WFM + (size_t)b*1664];
  for (int idx = t; idx < 416; idx += 256) {
    *(float4*)&wfs[idx*4] = wsrc[idx];
  }
  __syncthreads();
  const int c = t & 63, hh = t >> 6;
  const int h0 = hh*2, h1 = h0+1;
  const int cx = (c & 7) << 2;
  const float* fr = &fms[c*224];
  const float* w0p = &wfs[h0*208];
  const float* w1p = &wfs[h1*208];
  float a0 = 0.f, a1 = 0.f;
#pragma unroll 7
  for (int p4 = 0; p4 < 49; ++p4) {
    const float4 f  = *(const float4*)&fr[((p4 << 2) ^ cx)];
    const float4 u0 = *(const float4*)&w0p[p4*4];
    const float4 u1 = *(const float4*)&w1p[p4*4];
    a0 += f.x*u0.x + f.y*u0.y + f.z*u0.z + f.w*u0.w;
    a1 += f.x*u1.x + f.y*u1.y + f.z*u1.z + f.w*u1.w;
  }
  ws[WS_S + ((size_t)h0*256 + b)*1024 + c0 + c] = a0;
  ws[WS_S + ((size_t)h1*256 + b)*1024 + c0 + c] = a1;
}

// ---------------- KB-POS: pos GEMM, accumulates into WS_S ----------------
__global__ __launch_bounds__(256) void kb_pos(float* __restrict__ ws)
{
  __shared__ float As[64 * 108];
  __shared__ float Bs[64 * 108];
  const int ct = blockIdx.x, rt = blockIdx.y, t = threadIdx.x;
  const int c0 = ct*64, r0 = rt*64;
  const int bq = t >> 4, cq = t & 15;
  float acc[4][4] = {};
  for (int sub = 0; sub < 2; ++sub) {
    const int k0 = sub * 104;
    __syncthreads();
    for (int idx = t; idx < 1664; idx += 256) {
      const int r = idx / 26, q = idx - r*26;
      const float4 av = *(const float4*)&ws[WS_WPOS + (size_t)(r0 + r)*208 + k0 + q*4];
      float* da = &As[r*108 + q*4];
      da[0]=av.x; da[1]=av.y; da[2]=av.z; da[3]=av.w;
      const float4 bv = *(const float4*)&ws[WS_POST + (size_t)(c0 + r)*208 + k0 + q*4];
      float* db = &Bs[r*108 + q*4];
      db[0]=bv.x; db[1]=bv.y; db[2]=bv.z; db[3]=bv.w;
    }
    __syncthreads();
    for (int k4 = 0; k4 < 26; ++k4) {
      float4 av[4], bw[4];
#pragma unroll
      for (int i = 0; i < 4; ++i) av[i] = *(const float4*)&As[(bq + 16*i)*108 + k4*4];
#pragma unroll
      for (int j = 0; j < 4; ++j) bw[j] = *(const float4*)&Bs[(cq + 16*j)*108 + k4*4];
#pragma unroll
      for (int i = 0; i < 4; ++i)
#pragma unroll
        for (int j = 0; j < 4; ++j)
          acc[i][j] += av[i].x*bw[j].x + av[i].y*bw[j].y + av[i].z*bw[j].z + av[i].w*bw[j].w;
    }
  }
#pragma unroll
  for (int i = 0; i < 4; ++i) {
    const int rIdx = r0 + bq + 16*i;
    const int b = rIdx >> 3, h = rIdx & 7;
    float* srow = &ws[WS_S + ((size_t)h*256 + b)*1024];
#pragma unroll
    for (int j = 0; j < 4; ++j) {
      const int c = c0 + cq + 16*j;
      srow[c] += acc[i][j];
    }
  }
}

// ---------------- KV: ov partials (per-head GEMM, k-split) ----------------
__global__ __launch_bounds__(256) void kv_ov(
    const float* __restrict__ wv, float* __restrict__ ws)
{
  const int kt = blockIdx.x, bt = blockIdx.y, h = blockIdx.z, t = threadIdx.x;
  __shared__ float At[64 * 65];
  __shared__ float Bt[64 * 65];
  const int b0 = bt*64, k0 = kt*128;
  const int bq = t >> 4, dq = t & 15;
  float acc[4][4] = {};
  for (int sub = 0; sub < 2; ++sub) {
    const int kk0 = k0 + sub*64;
    __syncthreads();
    for (int r = 0; r < 4; ++r) {
      const int idx = t + 256*r;
      const int bi = idx >> 4, c4 = idx & 15;
      const float4 v = *(const float4*)&ws[WS_S + ((size_t)h*256 + b0 + bi)*1024 + kk0 + c4*4];
      float* d1 = &At[bi*65 + c4*4];
      d1[0]=v.x; d1[1]=v.y; d1[2]=v.z; d1[3]=v.w;
      const float4 w = *(const float4*)&wv[(size_t)(h*64 + bi)*1024 + kk0 + c4*4];
      float* d2 = &Bt[bi*65 + c4*4];
      d2[0]=w.x; d2[1]=w.y; d2[2]=w.z; d2[3]=w.w;
    }
    __syncthreads();
    for (int kk = 0; kk < 64; ++kk) {
      float av[4], bw[4];
#pragma unroll
      for (int i = 0; i < 4; ++i) av[i] = At[(bq*4+i)*65 + kk];
#pragma unroll
      for (int j = 0; j < 4; ++j) bw[j] = Bt[(dq*4+j)*65 + kk];
#pragma unroll
      for (int i = 0; i < 4; ++i)
#pragma unroll
        for (int j = 0; j < 4; ++j) acc[i][j] += av[i]*bw[j];
    }
  }
#pragma unroll
  for (int i = 0; i < 4; ++i) {
    *(float4*)&ws[WS_OVP + ((size_t)kt*256 + b0 + bq*4 + i)*512 + h*64 + dq*4] =
        make_float4(acc[i][0], acc[i][1], acc[i][2], acc[i][3]);
  }
}

// ---------------- KOR: reduce ov partials + bv -> OV (256x512) ----------------
__global__ __launch_bounds__(256) void kor_ovred(
    const float* __restrict__ bv, float* __restrict__ ws)
{
  const int b = blockIdx.x, t = threadIdx.x;
  for (int j = t; j < 512; j += 256) {
    float s = bv[j];
    for (int kt = 0; kt < 8; ++kt)
      s += ws[WS_OVP + ((size_t)kt*256 + b)*512 + j];
    ws[WS_OV + (size_t)b*512 + j] = s;
  }
}

// ---------------- KO: out1 partials (GEMM vs wo, k-split) ----------------
__global__ __launch_bounds__(256) void ko_out(
    const float* __restrict__ wo, float* __restrict__ ws)
{
  const int kt2 = blockIdx.x, ct = blockIdx.y, bt = blockIdx.z, t = threadIdx.x;
  __shared__ float At[64 * 65];
  __shared__ float Bt[64 * 65];
  const int b0 = bt*64, c0 = ct*64, j0 = kt2*128;
  const int bq = t >> 4, cq = t & 15;
  float acc[4][4] = {};
  for (int sub = 0; sub < 2; ++sub) {
    const int jj0 = j0 + sub*64;
    __syncthreads();
    for (int r = 0; r < 4; ++r) {
      const int idx = t + 256*r;
      const int bi = idx >> 4, j4 = idx & 15;
      const float4 p = *(const float4*)&ws[WS_OV + (size_t)(b0 + bi)*512 + jj0 + j4*4];
      float* d1 = &At[bi*65 + j4*4];
      d1[0]=p.x; d1[1]=p.y; d1[2]=p.z; d1[3]=p.w;
      const float4 w = *(const float4*)&wo[(size_t)(c0 + bi)*512 + jj0 + j4*4];
      float* d2 = &Bt[bi*65 + j4*4];
      d2[0]=w.x; d2[1]=w.y; d2[2]=w.z; d2[3]=w.w;
    }
    __syncthreads();
    for (int jj = 0; jj < 64; ++jj) {
      float av[4], bw[4];
#pragma unroll
      for (int i = 0; i < 4; ++i) av[i] = At[(bq*4+i)*65 + jj];
#pragma unroll
      for (int j = 0; j < 4; ++j) bw[j] = Bt[(cq*4+j)*65 + jj];
#pragma unroll
      for (int i = 0; i < 4; ++i)
#pragma unroll
        for (int j = 0; j < 4; ++j) acc[i][j] += av[i]*bw[j];
    }
  }
#pragma unroll
  for (int i = 0; i < 4; ++i) {
    *(float4*)&ws[WS_O1P + ((size_t)kt2*256 + b0 + bq*4 + i)*1024 + c0 + cq*4] =
        make_float4(acc[i][0], acc[i][1], acc[i][2], acc[i][3]);
  }
}

// ---------------- KLN: residual + LayerNorm ----------------
__global__ __launch_bounds__(256) void kln_final(
    const float* __restrict__ bo, const float* __restrict__ ln_g,
    const float* __restrict__ ln_b, const float* __restrict__ ws,
    float* __restrict__ out)
{
  const int b = blockIdx.x, t = threadIdx.x;
  __shared__ float rs[256], rq[256];
  float m0r[8];
#pragma unroll
  for (int j = 0; j < 8; ++j) m0r[j] = ws[WS_M0 + (size_t)b*8 + j];
  float r[4];
  float sum = 0.f, sumsq = 0.f;
  for (int k = 0; k < 4; ++k) {
    const int c = t + 256*k;
    float o1 = bo[c];
    for (int kt2 = 0; kt2 < 4; ++kt2)
      o1 += ws[WS_O1P + ((size_t)kt2*256 + b)*1024 + c];
    const float* wc = &ws[WS_WC + c*8];
    float qv = ws[WS_BCQ + c];
#pragma unroll
    for (int j = 0; j < 8; ++j) qv += wc[j]*m0r[j];
    const float res = qv + o1;
    r[k] = res; sum += res; sumsq += res*res;
  }
  rs[t] = sum; rq[t] = sumsq;
  __syncthreads();
  for (int s2 = 128; s2 >= 1; s2 >>= 1) {
    if (t < s2) { rs[t] += rs[t+s2]; rq[t] += rq[t+s2]; }
    __syncthreads();
  }
  const float mu  = rs[0] * (1.f/1024.f);
  const float var = rq[0] * (1.f/1024.f) - mu*mu;
  const float inv = rsqrtf(var + 1e-5f);
  for (int k = 0; k < 4; ++k) {
    const int c = t + 256*k;
    out[(size_t)b*1024 + c] = (r[k] - mu)*inv*ln_g[c] + ln_b[c];
  }
}

// ---------------- launcher ----------------
extern "C" void kernel_launch(void* const* d_in, const int* in_sizes, int n_in,
                              void* d_out, int out_size, void* d_ws, size_t ws_size,
                              hipStream_t stream)
{
  const float* fm   = (const float*)d_in[0];
  const float* lmap = (const float*)d_in[1];
  const float* w1 = (const float*)d_in[2];  const float* b1 = (const float*)d_in[3];
  const float* w2 = (const float*)d_in[4];  const float* b2 = (const float*)d_in[5];
  const float* w3 = (const float*)d_in[6];  const float* b3 = (const float*)d_in[7];
  const float* w4 = (const float*)d_in[8];  const float* b4 = (const float*)d_in[9];
  const float* w5 = (const float*)d_in[10]; const float* b5 = (const float*)d_in[11];
  const float* wq = (const float*)d_in[12]; const float* bq = (const float*)d_in[13];
  const float* wk = (const float*)d_in[14]; const float* bk = (const float*)d_in[15];
  const float* wv = (const float*)d_in[16]; const float* bv = (const float*)d_in[17];
  const float* wo = (const float*)d_in[18]; const float* bo = (const float*)d_in[19];
  const float* ln_g = (const float*)d_in[20]; const float* ln_b = (const float*)d_in[21];
  const float* pos_kv = (const float*)d_in[22]; const float* pos_q = (const float*)d_in[23];
  float* ws  = (float*)d_ws;
  float* out = (float*)d_out;

  kp1a_chain_post<<<dim3(17), dim3(256), 0, stream>>>(w1,b1,w2,b2,w3,b3,w4,b4,pos_kv,ws);
  kp1b_w5fold<<<dim3(32), dim3(256), 0, stream>>>(w5,b5,pos_q,ws);
  kp2a_qproj<<<dim3(128), dim3(256), 0, stream>>>(wq,bq,ws);
  kp2b_gfold<<<dim3(4,8), dim3(256), 0, stream>>>(wk,bk,pos_kv,ws);
  ka_att<<<dim3(8,256), dim3(256), 0, stream>>>(fm,lmap,ws);
  kaj_pfold<<<dim3(72), dim3(256), 0, stream>>>(ws);
  ksm_softmax<<<dim3(256), dim3(256), 0, stream>>>(ws);
  kb_fm<<<dim3(16,256), dim3(256), 0, stream>>>(fm,ws);
  kb_pos<<<dim3(16,32), dim3(256), 0, stream>>>(ws);
  kv_ov<<<dim3(8,4,8), dim3(256), 0, stream>>>(wv,ws);
  kor_ovred<<<dim3(256), dim3(256), 0, stream>>>(bv,ws);
  ko_out<<<dim3(4,16,4), dim3(256), 0, stream>>>(wo,ws);
  kln_final<<<dim3(256), dim3(256), 0, stream>>>(bo,ln_g,ln_b,ws,out);
}

// Round 6
// 225.917 us; speedup vs baseline: 1.2755x; 1.2755x over previous
//
#include <hip/hip_runtime.h>

// ---------------- workspace layout (float offsets) ----------------
#define WS_WC     ((size_t)0)        //  8192  Wc (1024x8)
#define WS_BCQ    ((size_t)8192)     //  1024  bc + pos_q[0]
#define WS_WQP    ((size_t)9216)     //  4096  Wq' (512x8)
#define WS_BQP    ((size_t)13312)    //   512  bq'
#define WS_U      ((size_t)13824)    //    64  u[h][8]   (bk fold)
#define WS_V      ((size_t)13888)    //     8  v[h]
#define WS_G      ((size_t)14336)    // 65536  G (8x1024x8)
#define WS_G0     ((size_t)79872)    //  8192  g0 (8x1024)
#define WS_POST   ((size_t)88064)    // 212992 pos_kv^T (1024x208, zero-padded)
#define WS_PSUM   ((size_t)301056)   //  1024  sum_{n=1..196} pos_kv[n]
#define WS_M0     ((size_t)302080)   //  2048  m0 (256x8)
#define WS_ATTP   ((size_t)304128)   // 1703936 att partials (256x4x8x208)
#define WS_WFM    ((size_t)2008064)  // 425984 fm-weights (256x8x208)
#define WS_WPOS   ((size_t)2434048)  // 425984 pos-weights (256x8x208)
#define WS_S      ((size_t)2860032)  // 2097152 s (8x256x1024)
#define WS_OVP    ((size_t)4957184)  // 1048576 ov partials (8x256x512)
#define WS_O1P    ((size_t)6005760)  // 1048576 out1 partials (4x256x1024)
#define WS_POSTP  ((size_t)7054336)  // 204800 pos_kv^T cols 1..196 (1024x200)
#define WS_OV     ((size_t)7259136)  // 131072 reduced ov (256x512)
// total 7390208 floats = 29.6 MB (ws allocation ~800 MB per fill counters)
#define WS_M4     WS_S    // scratch before kb writes WS_S
#define WS_PP     WS_OVP  // scratch (4ci x 8h x 18) before kv_ov writes OVP

// ---------------- KP1a: small chain stages + pos_kv transpose ----------------
__global__ __launch_bounds__(256) void kp1a_chain_post(
    const float* __restrict__ w1, const float* __restrict__ b1,
    const float* __restrict__ w2, const float* __restrict__ b2,
    const float* __restrict__ w3, const float* __restrict__ b3,
    const float* __restrict__ w4, const float* __restrict__ b4,
    const float* __restrict__ pos_kv, float* __restrict__ ws)
{
  __shared__ float shm[12864];   // 51.5 KB; union of both paths
  const int t = threadIdx.x;
  if (blockIdx.x == 0) {
    float* wt  = shm;            // W3 [128][65]=8320 / W4 tile [64][129]=8256
    float* M2s = shm + 8320;     // 512
    float* C2s = shm + 8832;     // 64
    float* M3s = shm + 8896;     // 1024
    float* C3s = shm + 9920;     // 128
    float* M4s = shm + 10048;    // 2048
    float* C4s = shm + 12096;    // 256

    for (int idx = t; idx < 2048; idx += 256) {        // W3 -> LDS
      const float4 v = ((const float4*)w3)[idx];
      const int r = idx >> 4, i = (idx & 15) * 4;
      float* d = &wt[r * 65 + i];
      d[0] = v.x; d[1] = v.y; d[2] = v.z; d[3] = v.w;
    }
    for (int idx = t; idx < 512; idx += 256) {
      const int o = idx >> 3, j = idx & 7;
      float a = 0.f;
      for (int i = 0; i < 32; ++i) a += w2[o*32+i] * w1[i*8+j];
      M2s[idx] = a;
    }
    if (t < 64) {
      float a = b2[t];
      for (int i = 0; i < 32; ++i) a += w2[t*32+i] * b1[i];
      C2s[t] = a;
    }
    __syncthreads();
    for (int idx = t; idx < 1024; idx += 256) {
      const int o = idx >> 3, j = idx & 7;
      const float* wr = &wt[o * 65];
      float a = 0.f;
      for (int i = 0; i < 64; ++i) a += wr[i] * M2s[i*8+j];
      M3s[idx] = a;
    }
    if (t < 128) {
      const float* wr = &wt[t * 65];
      float a = b3[t];
      for (int i = 0; i < 64; ++i) a += wr[i] * C2s[i];
      C3s[t] = a;
    }
    __syncthreads();
    for (int oc = 0; oc < 4; ++oc) {
      for (int idx = t; idx < 2048; idx += 256) {
        const float4 v = ((const float4*)w4)[oc*2048 + idx];
        const int r = idx >> 5, i = (idx & 31) * 4;
        float* d = &wt[r * 129 + i];
        d[0] = v.x; d[1] = v.y; d[2] = v.z; d[3] = v.w;
      }
      __syncthreads();
      for (int idx = t; idx < 512; idx += 256) {
        const int r = idx >> 3, j = idx & 7;
        const float* wr = &wt[r * 129];
        float a = 0.f;
        for (int i = 0; i < 128; ++i) a += wr[i] * M3s[i*8+j];
        M4s[(oc*64 + r)*8 + j] = a;
      }
      if (t < 64) {
        const float* wr = &wt[t * 129];
        float a = b4[oc*64 + t];
        for (int i = 0; i < 128; ++i) a += wr[i] * C3s[i];
        C4s[oc*64 + t] = a;
      }
      __syncthreads();
    }
    for (int idx = t; idx < 2048; idx += 256) ws[WS_M4 + idx] = M4s[idx];
    ws[WS_M4 + 2048 + t] = C4s[t];
  } else {
    const int c0 = (blockIdx.x - 1) * 64;
    const int c = t & 63, nb = t >> 6;
    for (int n = nb; n < 197; n += 4)
      shm[c*201 + n] = pos_kv[(size_t)n*1024 + c0 + c];
    __syncthreads();
    for (int idx = t; idx < 64*208; idx += 256) {
      int cc = idx / 208, n = idx - cc*208;
      ws[WS_POST + (size_t)(c0+cc)*208 + n] = (n < 197) ? shm[cc*201+n] : 0.f;
    }
    // shifted copy: POSTP[c][p] = pos_kv^T[c][p+1], p in 0..195 (stride 200)
    for (int idx = t; idx < 64*196; idx += 256) {
      int cc = idx / 196, p = idx - cc*196;
      ws[WS_POSTP + (size_t)(c0+cc)*200 + p] = shm[cc*201 + p + 1];
    }
    if (t < 64) {
      float s = 0.f;
      for (int n = 1; n < 197; ++n) s += shm[t*201 + n];
      ws[WS_PSUM + c0 + t] = s;
    }
  }
}

// ---------------- KP1b: W5 fold (1024x8), 32 rows/block ----------------
__global__ __launch_bounds__(256) void kp1b_w5fold(
    const float* __restrict__ w5, const float* __restrict__ b5,
    const float* __restrict__ pos_q, float* __restrict__ ws)
{
  __shared__ float wt[32 * 257];
  __shared__ float M4s[2304];
  const int t = threadIdx.x, ob = blockIdx.x;
  const int o0 = ob * 32;
  for (int idx = t; idx < 2304; idx += 256) M4s[idx] = ws[WS_M4 + idx];
  for (int idx = t; idx < 2048; idx += 256) {
    const float4 v = ((const float4*)w5)[(size_t)ob*2048 + idx];
    const int r = idx >> 6, i = (idx & 63) * 4;
    float* d = &wt[r * 257 + i];
    d[0] = v.x; d[1] = v.y; d[2] = v.z; d[3] = v.w;
  }
  __syncthreads();
  const int r = t >> 3, j = t & 7;
  const float* wr = &wt[r * 257];
  float a = 0.f;
  for (int i = 0; i < 256; ++i) a += wr[i] * M4s[i*8 + j];
  ws[WS_WC + (size_t)(o0 + r)*8 + j] = a;
  if (t < 32) {
    const float* wb = &wt[t * 257];
    float a2 = b5[o0 + t];
    for (int i = 0; i < 256; ++i) a2 += wb[i] * M4s[2048 + i];
    ws[WS_BCQ + o0 + t] = a2 + pos_q[o0 + t];
  }
}

// ---------------- KP2a: Wq' = wq @ Wc, bq' (wave per output row) ----------------
__global__ __launch_bounds__(256) void kp2a_qproj(
    const float* __restrict__ wq, const float* __restrict__ bq,
    float* __restrict__ ws)
{
  const int t = threadIdx.x;
  const int w = t >> 6, l = t & 63;
  const int o = blockIdx.x * 4 + w;
  const float* wqr = wq + (size_t)o * 1024;
  float acc[8] = {0,0,0,0,0,0,0,0};
  float accb = 0.f;
  for (int k = 0; k < 16; ++k) {
    const int c = l + 64*k;
    const float wv_ = wqr[c];
    const float4 a  = *(const float4*)&ws[WS_WC + (size_t)c*8];
    const float4 b2 = *(const float4*)&ws[WS_WC + (size_t)c*8 + 4];
    acc[0] += wv_*a.x;  acc[1] += wv_*a.y;  acc[2] += wv_*a.z;  acc[3] += wv_*a.w;
    acc[4] += wv_*b2.x; acc[5] += wv_*b2.y; acc[6] += wv_*b2.z; acc[7] += wv_*b2.w;
    accb += wv_ * ws[WS_BCQ + c];
  }
  for (int off = 32; off >= 1; off >>= 1) {
#pragma unroll
    for (int j = 0; j < 8; ++j) acc[j] += __shfl_xor(acc[j], off);
    accb += __shfl_xor(accb, off);
  }
  if (l == 0) {
#pragma unroll
    for (int j = 0; j < 8; ++j) ws[WS_WQP + (size_t)o*8 + j] = acc[j];
    ws[WS_BQP + o] = accb + bq[o];
  }
}

// ---------------- KP2b: G / g0 (c split over 4 blocks per head) + folds ------
__global__ __launch_bounds__(256) void kp2b_gfold(
    const float* __restrict__ wk, const float* __restrict__ bk,
    const float* __restrict__ pos_kv, float* __restrict__ ws)
{
  const int ci = blockIdx.x, h = blockIdx.y, t = threadIdx.x;
  __shared__ float WQs[512];
  __shared__ float BQs[64];
  __shared__ float red2[18 * 256];
  for (int idx = t; idx < 512; idx += 256) WQs[idx] = ws[WS_WQP + (size_t)h*512 + idx];
  if (t < 64) BQs[t] = ws[WS_BQP + h*64 + t];
  __syncthreads();

  const int c = ci*256 + t;
  float accG[8] = {0,0,0,0,0,0,0,0};
  float accg0 = 0.f;
  const float* wkc = wk + (size_t)h*64*1024 + c;
  for (int d = 0; d < 64; ++d) {
    const float wkv = wkc[(size_t)d*1024];
    const float4 qa = *(const float4*)&WQs[d*8];
    const float4 qb = *(const float4*)&WQs[d*8+4];
    accG[0] += wkv*qa.x; accG[1] += wkv*qa.y; accG[2] += wkv*qa.z; accG[3] += wkv*qa.w;
    accG[4] += wkv*qb.x; accG[5] += wkv*qb.y; accG[6] += wkv*qb.z; accG[7] += wkv*qb.w;
    accg0 += wkv * BQs[d];
  }
  *(float4*)&ws[WS_G + ((size_t)h*1024 + c)*8 + 0] = make_float4(accG[0],accG[1],accG[2],accG[3]);
  *(float4*)&ws[WS_G + ((size_t)h*1024 + c)*8 + 4] = make_float4(accG[4],accG[5],accG[6],accG[7]);
  ws[WS_G0 + (size_t)h*1024 + c] = accg0;

  const float z0 = pos_kv[c];
  const float zs = ws[WS_PSUM + c];
#pragma unroll
  for (int j = 0; j < 8; ++j) {
    red2[j*256 + t]     = accG[j]*z0;
    red2[(8+j)*256 + t] = accG[j]*zs;
  }
  red2[16*256 + t] = accg0*z0;
  red2[17*256 + t] = accg0*zs;
  __syncthreads();
  for (int s2 = 128; s2 >= 1; s2 >>= 1) {
    if (t < s2) {
#pragma unroll
      for (int j = 0; j < 18; ++j) red2[j*256 + t] += red2[j*256 + t + s2];
    }
    __syncthreads();
  }
  if (t == 0) {
    float* pp = &ws[WS_PP + ((size_t)ci*8 + h)*18];
#pragma unroll
    for (int j = 0; j < 18; ++j) pp[j] = red2[j*256];
  }

  if (ci == 0) {
    __syncthreads();
    const float bkv = (t < 64) ? bk[h*64 + t] : 0.f;
#pragma unroll
    for (int j = 0; j < 8; ++j)
      red2[j*256 + t] = (t < 64) ? bkv * WQs[t*8 + j] : 0.f;
    red2[8*256 + t] = (t < 64) ? bkv * BQs[t] : 0.f;
    __syncthreads();
    for (int s2 = 128; s2 >= 1; s2 >>= 1) {
      if (t < s2) {
#pragma unroll
        for (int j = 0; j < 9; ++j) red2[j*256 + t] += red2[j*256 + t + s2];
      }
      __syncthreads();
    }
    if (t == 0) {
#pragma unroll
      for (int j = 0; j < 8; ++j) ws[WS_U + h*8 + j] = red2[j*256];
      ws[WS_V + h] = red2[8*256];
    }
  }
}

// ---------------- KA: att raw dots (b, c-chunk); cc split across wave halves --
__global__ __launch_bounds__(256) void ka_att(
    const float* __restrict__ fm, const float* __restrict__ lmap,
    float* __restrict__ ws)
{
  const int ci = blockIdx.x, b = blockIdx.y, t = threadIdx.x;
  __shared__ float qk[256 * 8];
  __shared__ float pa[98 * 17];   // group-1 partials (stride 17: bank-conflict-free)
  __shared__ float m0s[8];
  {
    const int ch = t >> 5, lp = t & 31;
    float s = 0.f;
    for (int p = lp; p < 196; p += 32) s += lmap[((size_t)b*8 + ch)*196 + p];
    for (int off = 16; off >= 1; off >>= 1) s += __shfl_xor(s, off);
    if (lp == 0) m0s[ch] = s * (1.f/196.f);
  }
  __syncthreads();
  float m0r[8];
#pragma unroll
  for (int j = 0; j < 8; ++j) m0r[j] = m0s[j];
  const int c0 = ci * 256;
  {
    const int c = c0 + t;
#pragma unroll
    for (int h = 0; h < 8; ++h) {
      const float* gr = &ws[WS_G + ((size_t)h*1024 + c)*8];
      const float4 ga = *(const float4*)gr;
      const float4 gb = *(const float4*)(gr + 4);
      qk[t*8 + h] = ws[WS_G0 + (size_t)h*1024 + c]
                  + ga.x*m0r[0] + ga.y*m0r[1] + ga.z*m0r[2] + ga.w*m0r[3]
                  + gb.x*m0r[4] + gb.y*m0r[5] + gb.z*m0r[6] + gb.w*m0r[7];
    }
  }
  if (ci == 0 && t < 8) ws[WS_M0 + (size_t)b*8 + t] = m0s[t];
  __syncthreads();
  const int half = t >> 7, tl = t & 127;   // 2 wave-groups, cc-range split
  float a0[8] = {0,0,0,0,0,0,0,0};
  float a1[8] = {0,0,0,0,0,0,0,0};
  if (tl < 98) {
    const float* fmp = fm + ((size_t)b*1024 + c0 + half*128)*196 + 2*tl;
    const float* pp  = &ws[WS_POSTP + (size_t)(c0 + half*128)*200 + 2*tl];
    const float* qkh = &qk[half*128*8];
    for (int cc = 0; cc < 128; ++cc) {
      const float2 f = *(const float2*)&fmp[(size_t)cc*196];
      const float2 g = *(const float2*)&pp[(size_t)cc*200];
      const float x0 = f.x + g.x, x1 = f.y + g.y;
      const float4 qa = *(const float4*)&qkh[cc*8];
      const float4 qb = *(const float4*)&qkh[cc*8 + 4];
      a0[0] += qa.x*x0; a1[0] += qa.x*x1;
      a0[1] += qa.y*x0; a1[1] += qa.y*x1;
      a0[2] += qa.z*x0; a1[2] += qa.z*x1;
      a0[3] += qa.w*x0; a1[3] += qa.w*x1;
      a0[4] += qb.x*x0; a1[4] += qb.x*x1;
      a0[5] += qb.y*x0; a1[5] += qb.y*x1;
      a0[6] += qb.z*x0; a1[6] += qb.z*x1;
      a0[7] += qb.w*x0; a1[7] += qb.w*x1;
    }
  }
  if (half == 1 && tl < 98) {
    float* d = &pa[tl*17];
#pragma unroll
    for (int h = 0; h < 8; ++h) { d[h] = a0[h]; d[8+h] = a1[h]; }
  }
  __syncthreads();
  if (half == 0 && tl < 98) {
    const float* d = &pa[tl*17];
    float* ap = &ws[WS_ATTP + (((size_t)b*4 + ci)*8)*208 + 2*tl];
#pragma unroll
    for (int h = 0; h < 8; ++h)
      *(float2*)&ap[h*208] = make_float2(a0[h] + d[h], a1[h] + d[8+h]);
  }
}

// ---------------- KSM: softmax (incl. mean-token via S1 trick) ----------------
// (kp2c fold inlined: reads the 4 per-ci partial blocks from WS_PP directly)
__global__ __launch_bounds__(256) void ksm_softmax(float* __restrict__ ws)
{
  const int b = blockIdx.x, t = threadIdx.x;
  __shared__ float red[256 * 9];
  float m0r[8];
#pragma unroll
  for (int j = 0; j < 8; ++j) m0r[j] = ws[WS_M0 + (size_t)b*8 + j];
  float qbk[8], qs0[8], qss[8];
#pragma unroll
  for (int h = 0; h < 8; ++h) {
    float s1 = ws[WS_V + h];
#pragma unroll
    for (int j = 0; j < 8; ++j) s1 += ws[WS_U + h*8 + j] * m0r[j];
    qbk[h] = s1;
    float s2 = 0.f, s3 = 0.f;
    for (int ci = 0; ci < 4; ++ci) {
      const float* pp = &ws[WS_PP + ((size_t)ci*8 + h)*18];
      float v2 = pp[16], v3 = pp[17];
#pragma unroll
      for (int j = 0; j < 8; ++j) {
        v2 += pp[j]   * m0r[j];
        v3 += pp[8+j] * m0r[j];
      }
      s2 += v2; s3 += v3;
    }
    qs0[h] = s2; qss[h] = s3;
  }
  float a[8];
#pragma unroll
  for (int h = 0; h < 8; ++h) a[h] = 0.f;
  if (t < 196) {
#pragma unroll
    for (int h = 0; h < 8; ++h) {
      float s = 0.f;
      for (int ci = 0; ci < 4; ++ci)
        s += ws[WS_ATTP + (((size_t)b*4 + ci)*8 + h)*208 + t];
      a[h] = s;
    }
  }
#pragma unroll
  for (int h = 0; h < 8; ++h) red[t*9 + h] = a[h];
  __syncthreads();
  for (int s2 = 128; s2 >= 1; s2 >>= 1) {
    if (t < s2) {
#pragma unroll
      for (int h = 0; h < 8; ++h) red[t*9+h] += red[(t+s2)*9+h];
    }
    __syncthreads();
  }
  float fa[8], fa0[8];
#pragma unroll
  for (int h = 0; h < 8; ++h) {
    const float S1 = red[h];
    fa[h]  = (a[h] + qbk[h]) * 0.125f;
    const float a0r = (S1 - qss[h]) * (1.f/196.f) + qs0[h];
    fa0[h] = (a0r + qbk[h]) * 0.125f;
  }
  __syncthreads();
#pragma unroll
  for (int h = 0; h < 8; ++h) red[t*9+h] = (t < 196) ? fa[h] : -3.0e38f;
  __syncthreads();
  for (int s2 = 128; s2 >= 1; s2 >>= 1) {
    if (t < s2) {
#pragma unroll
      for (int h = 0; h < 8; ++h) red[t*9+h] = fmaxf(red[t*9+h], red[(t+s2)*9+h]);
    }
    __syncthreads();
  }
  float mh[8];
#pragma unroll
  for (int h = 0; h < 8; ++h) mh[h] = fmaxf(red[h], fa0[h]);
  __syncthreads();
  float eh[8], e0[8];
#pragma unroll
  for (int h = 0; h < 8; ++h) {
    eh[h] = (t < 196) ? __expf(fa[h] - mh[h]) : 0.f;
    e0[h] = __expf(fa0[h] - mh[h]);
    red[t*9+h] = eh[h];
  }
  __syncthreads();
  for (int s2 = 128; s2 >= 1; s2 >>= 1) {
    if (t < s2) {
#pragma unroll
      for (int h = 0; h < 8; ++h) red[t*9+h] += red[(t+s2)*9+h];
    }
    __syncthreads();
  }
#pragma unroll
  for (int h = 0; h < 8; ++h) {
    const float lh  = red[h] + e0[h];
    const float inv = 1.f / lh;
    const float w0  = e0[h] * inv;
    float* wfm = &ws[WS_WFM  + ((size_t)b*8 + h)*208];
    float* wpo = &ws[WS_WPOS + ((size_t)b*8 + h)*208];
    if (t < 196) {
      wfm[t]   = eh[h]*inv + w0*(1.f/196.f);
      wpo[t+1] = eh[h]*inv;
    } else if (t < 208) {
      wfm[t] = 0.f;
      if (t == 196) wpo[0] = w0;
      else          wpo[t] = 0.f;
    }
  }
}

// ---------------- KB-FM: fm weighted sums (swizzled LDS) ----------------
__global__ __launch_bounds__(256) void kb_fm(
    const float* __restrict__ fm, float* __restrict__ ws)
{
  __shared__ float fms[64 * 224];   // 56 float4 slots/row, slot XOR (c&7)
  __shared__ float wfs[1664];       // wfm[b] (8x208)
  const int cj = blockIdx.x, b = blockIdx.y, t = threadIdx.x;
  const int c0 = cj * 64;
  const float4* src = (const float4*)(fm + ((size_t)b*1024 + c0)*196);
  for (int idx = t; idx < 3136; idx += 256) {
    const float4 v = src[idx];
    const int c = idx / 49, q = idx - c*49;
    *(float4*)&fms[c*224 + ((q ^ (c & 7)) << 2)] = v;
  }
  const float4* wsrc = (const float4*)&ws[WS_WFM + (size_t)b*1664];
  for (int idx = t; idx < 416; idx += 256) {
    *(float4*)&wfs[idx*4] = wsrc[idx];
  }
  __syncthreads();
  const int c = t & 63, hh = t >> 6;
  const int h0 = hh*2, h1 = h0+1;
  const int cx = (c & 7) << 2;
  const float* fr = &fms[c*224];
  const float* w0p = &wfs[h0*208];
  const float* w1p = &wfs[h1*208];
  float a0 = 0.f, a1 = 0.f;
#pragma unroll 7
  for (int p4 = 0; p4 < 49; ++p4) {
    const float4 f  = *(const float4*)&fr[((p4 << 2) ^ cx)];
    const float4 u0 = *(const float4*)&w0p[p4*4];
    const float4 u1 = *(const float4*)&w1p[p4*4];
    a0 += f.x*u0.x + f.y*u0.y + f.z*u0.z + f.w*u0.w;
    a1 += f.x*u1.x + f.y*u1.y + f.z*u1.z + f.w*u1.w;
  }
  ws[WS_S + ((size_t)h0*256 + b)*1024 + c0 + c] = a0;
  ws[WS_S + ((size_t)h1*256 + b)*1024 + c0 + c] = a1;
}

// ---------------- KB-POS: pos GEMM, accumulates into WS_S ----------------
__global__ __launch_bounds__(256) void kb_pos(float* __restrict__ ws)
{
  __shared__ float As[64 * 108];
  __shared__ float Bs[64 * 108];
  const int ct = blockIdx.x, rt = blockIdx.y, t = threadIdx.x;
  const int c0 = ct*64, r0 = rt*64;
  const int bq = t >> 4, cq = t & 15;
  float acc[4][4] = {};
  for (int sub = 0; sub < 2; ++sub) {
    const int k0 = sub * 104;
    __syncthreads();
    for (int idx = t; idx < 1664; idx += 256) {
      const int r = idx / 26, q = idx - r*26;
      const float4 av = *(const float4*)&ws[WS_WPOS + (size_t)(r0 + r)*208 + k0 + q*4];
      float* da = &As[r*108 + q*4];
      da[0]=av.x; da[1]=av.y; da[2]=av.z; da[3]=av.w;
      const float4 bv = *(const float4*)&ws[WS_POST + (size_t)(c0 + r)*208 + k0 + q*4];
      float* db = &Bs[r*108 + q*4];
      db[0]=bv.x; db[1]=bv.y; db[2]=bv.z; db[3]=bv.w;
    }
    __syncthreads();
    for (int k4 = 0; k4 < 26; ++k4) {
      float4 av[4], bw[4];
#pragma unroll
      for (int i = 0; i < 4; ++i) av[i] = *(const float4*)&As[(bq + 16*i)*108 + k4*4];
#pragma unroll
      for (int j = 0; j < 4; ++j) bw[j] = *(const float4*)&Bs[(cq + 16*j)*108 + k4*4];
#pragma unroll
      for (int i = 0; i < 4; ++i)
#pragma unroll
        for (int j = 0; j < 4; ++j)
          acc[i][j] += av[i].x*bw[j].x + av[i].y*bw[j].y + av[i].z*bw[j].z + av[i].w*bw[j].w;
    }
  }
#pragma unroll
  for (int i = 0; i < 4; ++i) {
    const int rIdx = r0 + bq + 16*i;
    const int b = rIdx >> 3, h = rIdx & 7;
    float* srow = &ws[WS_S + ((size_t)h*256 + b)*1024];
#pragma unroll
    for (int j = 0; j < 4; ++j) {
      const int c = c0 + cq + 16*j;
      srow[c] += acc[i][j];
    }
  }
}

// ---------------- KV: ov partials (per-head GEMM, k-split) ----------------
__global__ __launch_bounds__(256) void kv_ov(
    const float* __restrict__ wv, float* __restrict__ ws)
{
  const int kt = blockIdx.x, bt = blockIdx.y, h = blockIdx.z, t = threadIdx.x;
  __shared__ float At[64 * 65];
  __shared__ float Bt[64 * 65];
  const int b0 = bt*64, k0 = kt*128;
  const int bq = t >> 4, dq = t & 15;
  float acc[4][4] = {};
  for (int sub = 0; sub < 2; ++sub) {
    const int kk0 = k0 + sub*64;
    __syncthreads();
    for (int r = 0; r < 4; ++r) {
      const int idx = t + 256*r;
      const int bi = idx >> 4, c4 = idx & 15;
      const float4 v = *(const float4*)&ws[WS_S + ((size_t)h*256 + b0 + bi)*1024 + kk0 + c4*4];
      float* d1 = &At[bi*65 + c4*4];
      d1[0]=v.x; d1[1]=v.y; d1[2]=v.z; d1[3]=v.w;
      const float4 w = *(const float4*)&wv[(size_t)(h*64 + bi)*1024 + kk0 + c4*4];
      float* d2 = &Bt[bi*65 + c4*4];
      d2[0]=w.x; d2[1]=w.y; d2[2]=w.z; d2[3]=w.w;
    }
    __syncthreads();
    for (int kk = 0; kk < 64; ++kk) {
      float av[4], bw[4];
#pragma unroll
      for (int i = 0; i < 4; ++i) av[i] = At[(bq*4+i)*65 + kk];
#pragma unroll
      for (int j = 0; j < 4; ++j) bw[j] = Bt[(dq*4+j)*65 + kk];
#pragma unroll
      for (int i = 0; i < 4; ++i)
#pragma unroll
        for (int j = 0; j < 4; ++j) acc[i][j] += av[i]*bw[j];
    }
  }
#pragma unroll
  for (int i = 0; i < 4; ++i) {
    *(float4*)&ws[WS_OVP + ((size_t)kt*256 + b0 + bq*4 + i)*512 + h*64 + dq*4] =
        make_float4(acc[i][0], acc[i][1], acc[i][2], acc[i][3]);
  }
}

// ---------------- KOR: reduce ov partials + bv -> OV (256x512) ----------------
__global__ __launch_bounds__(256) void kor_ovred(
    const float* __restrict__ bv, float* __restrict__ ws)
{
  const int b = blockIdx.x, t = threadIdx.x;
  for (int j = t; j < 512; j += 256) {
    float s = bv[j];
    for (int kt = 0; kt < 8; ++kt)
      s += ws[WS_OVP + ((size_t)kt*256 + b)*512 + j];
    ws[WS_OV + (size_t)b*512 + j] = s;
  }
}

// ---------------- KO: out1 partials (GEMM vs wo, k-split) ----------------
__global__ __launch_bounds__(256) void ko_out(
    const float* __restrict__ wo, float* __restrict__ ws)
{
  const int kt2 = blockIdx.x, ct = blockIdx.y, bt = blockIdx.z, t = threadIdx.x;
  __shared__ float At[64 * 65];
  __shared__ float Bt[64 * 65];
  const int b0 = bt*64, c0 = ct*64, j0 = kt2*128;
  const int bq = t >> 4, cq = t & 15;
  float acc[4][4] = {};
  for (int sub = 0; sub < 2; ++sub) {
    const int jj0 = j0 + sub*64;
    __syncthreads();
    for (int r = 0; r < 4; ++r) {
      const int idx = t + 256*r;
      const int bi = idx >> 4, j4 = idx & 15;
      const float4 p = *(const float4*)&ws[WS_OV + (size_t)(b0 + bi)*512 + jj0 + j4*4];
      float* d1 = &At[bi*65 + j4*4];
      d1[0]=p.x; d1[1]=p.y; d1[2]=p.z; d1[3]=p.w;
      const float4 w = *(const float4*)&wo[(size_t)(c0 + bi)*512 + jj0 + j4*4];
      float* d2 = &Bt[bi*65 + j4*4];
      d2[0]=w.x; d2[1]=w.y; d2[2]=w.z; d2[3]=w.w;
    }
    __syncthreads();
    for (int jj = 0; jj < 64; ++jj) {
      float av[4], bw[4];
#pragma unroll
      for (int i = 0; i < 4; ++i) av[i] = At[(bq*4+i)*65 + jj];
#pragma unroll
      for (int j = 0; j < 4; ++j) bw[j] = Bt[(cq*4+j)*65 + jj];
#pragma unroll
      for (int i = 0; i < 4; ++i)
#pragma unroll
        for (int j = 0; j < 4; ++j) acc[i][j] += av[i]*bw[j];
    }
  }
#pragma unroll
  for (int i = 0; i < 4; ++i) {
    *(float4*)&ws[WS_O1P + ((size_t)kt2*256 + b0 + bq*4 + i)*1024 + c0 + cq*4] =
        make_float4(acc[i][0], acc[i][1], acc[i][2], acc[i][3]);
  }
}

// ---------------- KLN: residual + LayerNorm ----------------
__global__ __launch_bounds__(256) void kln_final(
    const float* __restrict__ bo, const float* __restrict__ ln_g,
    const float* __restrict__ ln_b, const float* __restrict__ ws,
    float* __restrict__ out)
{
  const int b = blockIdx.x, t = threadIdx.x;
  __shared__ float rs[256], rq[256];
  float m0r[8];
#pragma unroll
  for (int j = 0; j < 8; ++j) m0r[j] = ws[WS_M0 + (size_t)b*8 + j];
  float r[4];
  float sum = 0.f, sumsq = 0.f;
  for (int k = 0; k < 4; ++k) {
    const int c = t + 256*k;
    float o1 = bo[c];
    for (int kt2 = 0; kt2 < 4; ++kt2)
      o1 += ws[WS_O1P + ((size_t)kt2*256 + b)*1024 + c];
    const float* wc = &ws[WS_WC + c*8];
    float qv = ws[WS_BCQ + c];
#pragma unroll
    for (int j = 0; j < 8; ++j) qv += wc[j]*m0r[j];
    const float res = qv + o1;
    r[k] = res; sum += res; sumsq += res*res;
  }
  rs[t] = sum; rq[t] = sumsq;
  __syncthreads();
  for (int s2 = 128; s2 >= 1; s2 >>= 1) {
    if (t < s2) { rs[t] += rs[t+s2]; rq[t] += rq[t+s2]; }
    __syncthreads();
  }
  const float mu  = rs[0] * (1.f/1024.f);
  const float var = rq[0] * (1.f/1024.f) - mu*mu;
  const float inv = rsqrtf(var + 1e-5f);
  for (int k = 0; k < 4; ++k) {
    const int c = t + 256*k;
    out[(size_t)b*1024 + c] = (r[k] - mu)*inv*ln_g[c] + ln_b[c];
  }
}

// ---------------- launcher ----------------
extern "C" void kernel_launch(void* const* d_in, const int* in_sizes, int n_in,
                              void* d_out, int out_size, void* d_ws, size_t ws_size,
                              hipStream_t stream)
{
  const float* fm   = (const float*)d_in[0];
  const float* lmap = (const float*)d_in[1];
  const float* w1 = (const float*)d_in[2];  const float* b1 = (const float*)d_in[3];
  const float* w2 = (const float*)d_in[4];  const float* b2 = (const float*)d_in[5];
  const float* w3 = (const float*)d_in[6];  const float* b3 = (const float*)d_in[7];
  const float* w4 = (const float*)d_in[8];  const float* b4 = (const float*)d_in[9];
  const float* w5 = (const float*)d_in[10]; const float* b5 = (const float*)d_in[11];
  const float* wq = (const float*)d_in[12]; const float* bq = (const float*)d_in[13];
  const float* wk = (const float*)d_in[14]; const float* bk = (const float*)d_in[15];
  const float* wv = (const float*)d_in[16]; const float* bv = (const float*)d_in[17];
  const float* wo = (const float*)d_in[18]; const float* bo = (const float*)d_in[19];
  const float* ln_g = (const float*)d_in[20]; const float* ln_b = (const float*)d_in[21];
  const float* pos_kv = (const float*)d_in[22]; const float* pos_q = (const float*)d_in[23];
  float* ws  = (float*)d_ws;
  float* out = (float*)d_out;

  kp1a_chain_post<<<dim3(17), dim3(256), 0, stream>>>(w1,b1,w2,b2,w3,b3,w4,b4,pos_kv,ws);
  kp1b_w5fold<<<dim3(32), dim3(256), 0, stream>>>(w5,b5,pos_q,ws);
  kp2a_qproj<<<dim3(128), dim3(256), 0, stream>>>(wq,bq,ws);
  kp2b_gfold<<<dim3(4,8), dim3(256), 0, stream>>>(wk,bk,pos_kv,ws);
  ka_att<<<dim3(4,256), dim3(256), 0, stream>>>(fm,lmap,ws);
  ksm_softmax<<<dim3(256), dim3(256), 0, stream>>>(ws);
  kb_fm<<<dim3(16,256), dim3(256), 0, stream>>>(fm,ws);
  kb_pos<<<dim3(16,32), dim3(256), 0, stream>>>(ws);
  kv_ov<<<dim3(8,4,8), dim3(256), 0, stream>>>(wv,ws);
  kor_ovred<<<dim3(256), dim3(256), 0, stream>>>(bv,ws);
  ko_out<<<dim3(4,16,4), dim3(256), 0, stream>>>(wo,ws);
  kln_final<<<dim3(256), dim3(256), 0, stream>>>(bo,ln_g,ln_b,ws,out);
}

// Round 7
// 217.707 us; speedup vs baseline: 1.3236x; 1.0377x over previous
//
#include <hip/hip_runtime.h>

// ---------------- workspace layout (float offsets) ----------------
#define WS_WC     ((size_t)0)        //  8192  Wc (1024x8)
#define WS_BCQ    ((size_t)8192)     //  1024  bc + pos_q[0]
#define WS_WQP    ((size_t)9216)     //  4096  Wq' (512x8)
#define WS_BQP    ((size_t)13312)    //   512  bq'
#define WS_U      ((size_t)13824)    //    64  u[h][8]   (bk fold)
#define WS_V      ((size_t)13888)    //     8  v[h]
#define WS_G      ((size_t)14336)    // 65536  G (8x1024x8)
#define WS_G0     ((size_t)79872)    //  8192  g0 (8x1024)
#define WS_POST   ((size_t)88064)    // 212992 pos_kv^T (1024x208, zero-padded)
#define WS_PSUM   ((size_t)301056)   //  1024  sum_{n=1..196} pos_kv[n]
#define WS_M0     ((size_t)302080)   //  2048  m0 (256x8)
#define WS_ATTP   ((size_t)304128)   // 1703936 att partials (256x4x8x208)
#define WS_WFM    ((size_t)2008064)  // 425984 fm-weights (256x8x208)
#define WS_WPOS   ((size_t)2434048)  // 425984 pos-weights (256x8x208)
#define WS_S      ((size_t)2860032)  // 2097152 s (8x256x1024)
#define WS_OVP    ((size_t)4957184)  // 1048576 ov partials (8x256x512)
#define WS_O1P    ((size_t)6005760)  // 1048576 out1 partials (4x256x1024)
#define WS_POSTP  ((size_t)7054336)  // 204800 pos_kv^T cols 1..196 (1024x200)
#define WS_OV     ((size_t)7259136)  // 131072 reduced ov (256x512)
// total 7390208 floats = 29.6 MB (ws allocation ~800 MB per fill counters)
#define WS_M4     WS_S    // scratch before kb writes WS_S
#define WS_PP     WS_OVP  // scratch (4ci x 8h x 18) before kv_ov writes OVP

// ---------------- KP1a: small chain stages + pos_kv transpose ----------------
__global__ __launch_bounds__(256) void kp1a_chain_post(
    const float* __restrict__ w1, const float* __restrict__ b1,
    const float* __restrict__ w2, const float* __restrict__ b2,
    const float* __restrict__ w3, const float* __restrict__ b3,
    const float* __restrict__ w4, const float* __restrict__ b4,
    const float* __restrict__ pos_kv, float* __restrict__ ws)
{
  __shared__ float shm[12864];   // 51.5 KB; union of both paths
  const int t = threadIdx.x;
  if (blockIdx.x == 0) {
    float* wt  = shm;            // W3 [128][65]=8320 / W4 tile [64][129]=8256
    float* M2s = shm + 8320;     // 512
    float* C2s = shm + 8832;     // 64
    float* M3s = shm + 8896;     // 1024
    float* C3s = shm + 9920;     // 128
    float* M4s = shm + 10048;    // 2048
    float* C4s = shm + 12096;    // 256

    for (int idx = t; idx < 2048; idx += 256) {        // W3 -> LDS
      const float4 v = ((const float4*)w3)[idx];
      const int r = idx >> 4, i = (idx & 15) * 4;
      float* d = &wt[r * 65 + i];
      d[0] = v.x; d[1] = v.y; d[2] = v.z; d[3] = v.w;
    }
    for (int idx = t; idx < 512; idx += 256) {
      const int o = idx >> 3, j = idx & 7;
      float a = 0.f;
      for (int i = 0; i < 32; ++i) a += w2[o*32+i] * w1[i*8+j];
      M2s[idx] = a;
    }
    if (t < 64) {
      float a = b2[t];
      for (int i = 0; i < 32; ++i) a += w2[t*32+i] * b1[i];
      C2s[t] = a;
    }
    __syncthreads();
    for (int idx = t; idx < 1024; idx += 256) {
      const int o = idx >> 3, j = idx & 7;
      const float* wr = &wt[o * 65];
      float a = 0.f;
      for (int i = 0; i < 64; ++i) a += wr[i] * M2s[i*8+j];
      M3s[idx] = a;
    }
    if (t < 128) {
      const float* wr = &wt[t * 65];
      float a = b3[t];
      for (int i = 0; i < 64; ++i) a += wr[i] * C2s[i];
      C3s[t] = a;
    }
    __syncthreads();
    for (int oc = 0; oc < 4; ++oc) {
      for (int idx = t; idx < 2048; idx += 256) {
        const float4 v = ((const float4*)w4)[oc*2048 + idx];
        const int r = idx >> 5, i = (idx & 31) * 4;
        float* d = &wt[r * 129 + i];
        d[0] = v.x; d[1] = v.y; d[2] = v.z; d[3] = v.w;
      }
      __syncthreads();
      for (int idx = t; idx < 512; idx += 256) {
        const int r = idx >> 3, j = idx & 7;
        const float* wr = &wt[r * 129];
        float a = 0.f;
        for (int i = 0; i < 128; ++i) a += wr[i] * M3s[i*8+j];
        M4s[(oc*64 + r)*8 + j] = a;
      }
      if (t < 64) {
        const float* wr = &wt[t * 129];
        float a = b4[oc*64 + t];
        for (int i = 0; i < 128; ++i) a += wr[i] * C3s[i];
        C4s[oc*64 + t] = a;
      }
      __syncthreads();
    }
    for (int idx = t; idx < 2048; idx += 256) ws[WS_M4 + idx] = M4s[idx];
    ws[WS_M4 + 2048 + t] = C4s[t];
  } else {
    const int c0 = (blockIdx.x - 1) * 64;
    const int c = t & 63, nb = t >> 6;
    for (int n = nb; n < 197; n += 4)
      shm[c*201 + n] = pos_kv[(size_t)n*1024 + c0 + c];
    __syncthreads();
    for (int idx = t; idx < 64*208; idx += 256) {
      int cc = idx / 208, n = idx - cc*208;
      ws[WS_POST + (size_t)(c0+cc)*208 + n] = (n < 197) ? shm[cc*201+n] : 0.f;
    }
    // shifted copy: POSTP[c][p] = pos_kv^T[c][p+1], p in 0..195 (stride 200)
    for (int idx = t; idx < 64*196; idx += 256) {
      int cc = idx / 196, p = idx - cc*196;
      ws[WS_POSTP + (size_t)(c0+cc)*200 + p] = shm[cc*201 + p + 1];
    }
    if (t < 64) {
      float s = 0.f;
      for (int n = 1; n < 197; ++n) s += shm[t*201 + n];
      ws[WS_PSUM + c0 + t] = s;
    }
  }
}

// ---------------- KP1b: W5 fold (1024x8), 32 rows/block ----------------
__global__ __launch_bounds__(256) void kp1b_w5fold(
    const float* __restrict__ w5, const float* __restrict__ b5,
    const float* __restrict__ pos_q, float* __restrict__ ws)
{
  __shared__ float wt[32 * 257];
  __shared__ float M4s[2304];
  const int t = threadIdx.x, ob = blockIdx.x;
  const int o0 = ob * 32;
  for (int idx = t; idx < 2304; idx += 256) M4s[idx] = ws[WS_M4 + idx];
  for (int idx = t; idx < 2048; idx += 256) {
    const float4 v = ((const float4*)w5)[(size_t)ob*2048 + idx];
    const int r = idx >> 6, i = (idx & 63) * 4;
    float* d = &wt[r * 257 + i];
    d[0] = v.x; d[1] = v.y; d[2] = v.z; d[3] = v.w;
  }
  __syncthreads();
  const int r = t >> 3, j = t & 7;
  const float* wr = &wt[r * 257];
  float a = 0.f;
  for (int i = 0; i < 256; ++i) a += wr[i] * M4s[i*8 + j];
  ws[WS_WC + (size_t)(o0 + r)*8 + j] = a;
  if (t < 32) {
    const float* wb = &wt[t * 257];
    float a2 = b5[o0 + t];
    for (int i = 0; i < 256; ++i) a2 += wb[i] * M4s[2048 + i];
    ws[WS_BCQ + o0 + t] = a2 + pos_q[o0 + t];
  }
}

// ---------------- KP2a: Wq' = wq @ Wc, bq' (wave per output row) ----------------
__global__ __launch_bounds__(256) void kp2a_qproj(
    const float* __restrict__ wq, const float* __restrict__ bq,
    float* __restrict__ ws)
{
  const int t = threadIdx.x;
  const int w = t >> 6, l = t & 63;
  const int o = blockIdx.x * 4 + w;
  const float* wqr = wq + (size_t)o * 1024;
  float acc[8] = {0,0,0,0,0,0,0,0};
  float accb = 0.f;
  for (int k = 0; k < 16; ++k) {
    const int c = l + 64*k;
    const float wv_ = wqr[c];
    const float4 a  = *(const float4*)&ws[WS_WC + (size_t)c*8];
    const float4 b2 = *(const float4*)&ws[WS_WC + (size_t)c*8 + 4];
    acc[0] += wv_*a.x;  acc[1] += wv_*a.y;  acc[2] += wv_*a.z;  acc[3] += wv_*a.w;
    acc[4] += wv_*b2.x; acc[5] += wv_*b2.y; acc[6] += wv_*b2.z; acc[7] += wv_*b2.w;
    accb += wv_ * ws[WS_BCQ + c];
  }
  for (int off = 32; off >= 1; off >>= 1) {
#pragma unroll
    for (int j = 0; j < 8; ++j) acc[j] += __shfl_xor(acc[j], off);
    accb += __shfl_xor(accb, off);
  }
  if (l == 0) {
#pragma unroll
    for (int j = 0; j < 8; ++j) ws[WS_WQP + (size_t)o*8 + j] = acc[j];
    ws[WS_BQP + o] = accb + bq[o];
  }
}

// ---------------- KP2b: G / g0 (c split over 4 blocks per head) + folds ------
__global__ __launch_bounds__(256) void kp2b_gfold(
    const float* __restrict__ wk, const float* __restrict__ bk,
    const float* __restrict__ pos_kv, float* __restrict__ ws)
{
  const int ci = blockIdx.x, h = blockIdx.y, t = threadIdx.x;
  __shared__ float WQs[512];
  __shared__ float BQs[64];
  __shared__ float red2[18 * 256];
  for (int idx = t; idx < 512; idx += 256) WQs[idx] = ws[WS_WQP + (size_t)h*512 + idx];
  if (t < 64) BQs[t] = ws[WS_BQP + h*64 + t];
  __syncthreads();

  const int c = ci*256 + t;
  float accG[8] = {0,0,0,0,0,0,0,0};
  float accg0 = 0.f;
  const float* wkc = wk + (size_t)h*64*1024 + c;
  for (int d = 0; d < 64; ++d) {
    const float wkv = wkc[(size_t)d*1024];
    const float4 qa = *(const float4*)&WQs[d*8];
    const float4 qb = *(const float4*)&WQs[d*8+4];
    accG[0] += wkv*qa.x; accG[1] += wkv*qa.y; accG[2] += wkv*qa.z; accG[3] += wkv*qa.w;
    accG[4] += wkv*qb.x; accG[5] += wkv*qb.y; accG[6] += wkv*qb.z; accG[7] += wkv*qb.w;
    accg0 += wkv * BQs[d];
  }
  *(float4*)&ws[WS_G + ((size_t)h*1024 + c)*8 + 0] = make_float4(accG[0],accG[1],accG[2],accG[3]);
  *(float4*)&ws[WS_G + ((size_t)h*1024 + c)*8 + 4] = make_float4(accG[4],accG[5],accG[6],accG[7]);
  ws[WS_G0 + (size_t)h*1024 + c] = accg0;

  const float z0 = pos_kv[c];
  const float zs = ws[WS_PSUM + c];
#pragma unroll
  for (int j = 0; j < 8; ++j) {
    red2[j*256 + t]     = accG[j]*z0;
    red2[(8+j)*256 + t] = accG[j]*zs;
  }
  red2[16*256 + t] = accg0*z0;
  red2[17*256 + t] = accg0*zs;
  __syncthreads();
  for (int s2 = 128; s2 >= 1; s2 >>= 1) {
    if (t < s2) {
#pragma unroll
      for (int j = 0; j < 18; ++j) red2[j*256 + t] += red2[j*256 + t + s2];
    }
    __syncthreads();
  }
  if (t == 0) {
    float* pp = &ws[WS_PP + ((size_t)ci*8 + h)*18];
#pragma unroll
    for (int j = 0; j < 18; ++j) pp[j] = red2[j*256];
  }

  if (ci == 0) {
    __syncthreads();
    const float bkv = (t < 64) ? bk[h*64 + t] : 0.f;
#pragma unroll
    for (int j = 0; j < 8; ++j)
      red2[j*256 + t] = (t < 64) ? bkv * WQs[t*8 + j] : 0.f;
    red2[8*256 + t] = (t < 64) ? bkv * BQs[t] : 0.f;
    __syncthreads();
    for (int s2 = 128; s2 >= 1; s2 >>= 1) {
      if (t < s2) {
#pragma unroll
        for (int j = 0; j < 9; ++j) red2[j*256 + t] += red2[j*256 + t + s2];
      }
      __syncthreads();
    }
    if (t == 0) {
#pragma unroll
      for (int j = 0; j < 8; ++j) ws[WS_U + h*8 + j] = red2[j*256];
      ws[WS_V + h] = red2[8*256];
    }
  }
}

// ---------------- KA: att raw dots (b, c-chunk); cc split across 4 waves -----
// 4 wave-quarters each own 64 cc's; 49 active lanes/wave do 4 pixels (float4).
__global__ __launch_bounds__(256) void ka_att(
    const float* __restrict__ fm, const float* __restrict__ lmap,
    float* __restrict__ ws)
{
  const int ci = blockIdx.x, b = blockIdx.y, t = threadIdx.x;
  __shared__ float qk[256 * 8];
  __shared__ float pa[3 * 49 * 33];   // quarters 1..3 partials (stride 33: conflict-free)
  __shared__ float m0s[8];
  {
    const int ch = t >> 5, lp = t & 31;
    float s = 0.f;
    for (int p = lp; p < 196; p += 32) s += lmap[((size_t)b*8 + ch)*196 + p];
    for (int off = 16; off >= 1; off >>= 1) s += __shfl_xor(s, off);
    if (lp == 0) m0s[ch] = s * (1.f/196.f);
  }
  __syncthreads();
  float m0r[8];
#pragma unroll
  for (int j = 0; j < 8; ++j) m0r[j] = m0s[j];
  const int c0 = ci * 256;
  {
    const int c = c0 + t;
#pragma unroll
    for (int h = 0; h < 8; ++h) {
      const float* gr = &ws[WS_G + ((size_t)h*1024 + c)*8];
      const float4 ga = *(const float4*)gr;
      const float4 gb = *(const float4*)(gr + 4);
      qk[t*8 + h] = ws[WS_G0 + (size_t)h*1024 + c]
                  + ga.x*m0r[0] + ga.y*m0r[1] + ga.z*m0r[2] + ga.w*m0r[3]
                  + gb.x*m0r[4] + gb.y*m0r[5] + gb.z*m0r[6] + gb.w*m0r[7];
    }
  }
  if (ci == 0 && t < 8) ws[WS_M0 + (size_t)b*8 + t] = m0s[t];
  __syncthreads();
  const int q = t >> 6, tl = t & 63;     // 4 wave-quarters, cc-range split
  float a0[8] = {0,0,0,0,0,0,0,0};
  float a1[8] = {0,0,0,0,0,0,0,0};
  float a2[8] = {0,0,0,0,0,0,0,0};
  float a3[8] = {0,0,0,0,0,0,0,0};
  if (tl < 49) {
    const float* fmp = fm + ((size_t)b*1024 + c0 + q*64)*196 + 4*tl;
    const float* pp  = &ws[WS_POSTP + (size_t)(c0 + q*64)*200 + 4*tl];
    const float* qkh = &qk[q*64*8];
#pragma unroll 2
    for (int cc = 0; cc < 64; ++cc) {
      const float4 f = *(const float4*)&fmp[(size_t)cc*196];
      const float4 g = *(const float4*)&pp[(size_t)cc*200];
      const float x0 = f.x + g.x, x1 = f.y + g.y, x2 = f.z + g.z, x3 = f.w + g.w;
      const float4 qa = *(const float4*)&qkh[cc*8];
      const float4 qb = *(const float4*)&qkh[cc*8 + 4];
      a0[0] += qa.x*x0; a1[0] += qa.x*x1; a2[0] += qa.x*x2; a3[0] += qa.x*x3;
      a0[1] += qa.y*x0; a1[1] += qa.y*x1; a2[1] += qa.y*x2; a3[1] += qa.y*x3;
      a0[2] += qa.z*x0; a1[2] += qa.z*x1; a2[2] += qa.z*x2; a3[2] += qa.z*x3;
      a0[3] += qa.w*x0; a1[3] += qa.w*x1; a2[3] += qa.w*x2; a3[3] += qa.w*x3;
      a0[4] += qb.x*x0; a1[4] += qb.x*x1; a2[4] += qb.x*x2; a3[4] += qb.x*x3;
      a0[5] += qb.y*x0; a1[5] += qb.y*x1; a2[5] += qb.y*x2; a3[5] += qb.y*x3;
      a0[6] += qb.z*x0; a1[6] += qb.z*x1; a2[6] += qb.z*x2; a3[6] += qb.z*x3;
      a0[7] += qb.w*x0; a1[7] += qb.w*x1; a2[7] += qb.w*x2; a3[7] += qb.w*x3;
    }
  }
  if (q > 0 && tl < 49) {
    float* d = &pa[((q-1)*49 + tl)*33];
#pragma unroll
    for (int h = 0; h < 8; ++h) {
      d[h]    = a0[h];
      d[8+h]  = a1[h];
      d[16+h] = a2[h];
      d[24+h] = a3[h];
    }
  }
  __syncthreads();
  if (q == 0 && tl < 49) {
#pragma unroll
    for (int k = 0; k < 3; ++k) {
      const float* d = &pa[(k*49 + tl)*33];
#pragma unroll
      for (int h = 0; h < 8; ++h) {
        a0[h] += d[h];
        a1[h] += d[8+h];
        a2[h] += d[16+h];
        a3[h] += d[24+h];
      }
    }
    float* ap = &ws[WS_ATTP + (((size_t)b*4 + ci)*8)*208 + 4*tl];
#pragma unroll
    for (int h = 0; h < 8; ++h)
      *(float4*)&ap[h*208] = make_float4(a0[h], a1[h], a2[h], a3[h]);
  }
}

// ---------------- KSM: softmax (incl. mean-token via S1 trick) ----------------
// (kp2c fold inlined: reads the 4 per-ci partial blocks from WS_PP directly)
__global__ __launch_bounds__(256) void ksm_softmax(float* __restrict__ ws)
{
  const int b = blockIdx.x, t = threadIdx.x;
  __shared__ float red[256 * 9];
  float m0r[8];
#pragma unroll
  for (int j = 0; j < 8; ++j) m0r[j] = ws[WS_M0 + (size_t)b*8 + j];
  float qbk[8], qs0[8], qss[8];
#pragma unroll
  for (int h = 0; h < 8; ++h) {
    float s1 = ws[WS_V + h];
#pragma unroll
    for (int j = 0; j < 8; ++j) s1 += ws[WS_U + h*8 + j] * m0r[j];
    qbk[h] = s1;
    float s2 = 0.f, s3 = 0.f;
    for (int ci = 0; ci < 4; ++ci) {
      const float* pp = &ws[WS_PP + ((size_t)ci*8 + h)*18];
      float v2 = pp[16], v3 = pp[17];
#pragma unroll
      for (int j = 0; j < 8; ++j) {
        v2 += pp[j]   * m0r[j];
        v3 += pp[8+j] * m0r[j];
      }
      s2 += v2; s3 += v3;
    }
    qs0[h] = s2; qss[h] = s3;
  }
  float a[8];
#pragma unroll
  for (int h = 0; h < 8; ++h) a[h] = 0.f;
  if (t < 196) {
#pragma unroll
    for (int h = 0; h < 8; ++h) {
      float s = 0.f;
      for (int ci = 0; ci < 4; ++ci)
        s += ws[WS_ATTP + (((size_t)b*4 + ci)*8 + h)*208 + t];
      a[h] = s;
    }
  }
#pragma unroll
  for (int h = 0; h < 8; ++h) red[t*9 + h] = a[h];
  __syncthreads();
  for (int s2 = 128; s2 >= 1; s2 >>= 1) {
    if (t < s2) {
#pragma unroll
      for (int h = 0; h < 8; ++h) red[t*9+h] += red[(t+s2)*9+h];
    }
    __syncthreads();
  }
  float fa[8], fa0[8];
#pragma unroll
  for (int h = 0; h < 8; ++h) {
    const float S1 = red[h];
    fa[h]  = (a[h] + qbk[h]) * 0.125f;
    const float a0r = (S1 - qss[h]) * (1.f/196.f) + qs0[h];
    fa0[h] = (a0r + qbk[h]) * 0.125f;
  }
  __syncthreads();
#pragma unroll
  for (int h = 0; h < 8; ++h) red[t*9+h] = (t < 196) ? fa[h] : -3.0e38f;
  __syncthreads();
  for (int s2 = 128; s2 >= 1; s2 >>= 1) {
    if (t < s2) {
#pragma unroll
      for (int h = 0; h < 8; ++h) red[t*9+h] = fmaxf(red[t*9+h], red[(t+s2)*9+h]);
    }
    __syncthreads();
  }
  float mh[8];
#pragma unroll
  for (int h = 0; h < 8; ++h) mh[h] = fmaxf(red[h], fa0[h]);
  __syncthreads();
  float eh[8], e0[8];
#pragma unroll
  for (int h = 0; h < 8; ++h) {
    eh[h] = (t < 196) ? __expf(fa[h] - mh[h]) : 0.f;
    e0[h] = __expf(fa0[h] - mh[h]);
    red[t*9+h] = eh[h];
  }
  __syncthreads();
  for (int s2 = 128; s2 >= 1; s2 >>= 1) {
    if (t < s2) {
#pragma unroll
      for (int h = 0; h < 8; ++h) red[t*9+h] += red[(t+s2)*9+h];
    }
    __syncthreads();
  }
#pragma unroll
  for (int h = 0; h < 8; ++h) {
    const float lh  = red[h] + e0[h];
    const float inv = 1.f / lh;
    const float w0  = e0[h] * inv;
    float* wfm = &ws[WS_WFM  + ((size_t)b*8 + h)*208];
    float* wpo = &ws[WS_WPOS + ((size_t)b*8 + h)*208];
    if (t < 196) {
      wfm[t]   = eh[h]*inv + w0*(1.f/196.f);
      wpo[t+1] = eh[h]*inv;
    } else if (t < 208) {
      wfm[t] = 0.f;
      if (t == 196) wpo[0] = w0;
      else          wpo[t] = 0.f;
    }
  }
}

// ---------------- KB-FM: fm weighted sums (swizzled LDS, batched staging) -----
__global__ __launch_bounds__(256) void kb_fm(
    const float* __restrict__ fm, float* __restrict__ ws)
{
  __shared__ float fms[64 * 224];   // 56 float4 slots/row, slot XOR (c&7)
  __shared__ float wfs[1664];       // wfm[b] (8x208)
  const int cj = blockIdx.x, b = blockIdx.y, t = threadIdx.x;
  const int c0 = cj * 64;
  const float4* src = (const float4*)(fm + ((size_t)b*1024 + c0)*196);
  // staging: batches of 4 in-flight float4 loads (3136 = 12*256 + 64)
  for (int r = 0; r < 3; ++r) {
    float4 v[4];
#pragma unroll
    for (int u = 0; u < 4; ++u) v[u] = src[t + (r*4 + u)*256];
#pragma unroll
    for (int u = 0; u < 4; ++u) {
      const int idx = t + (r*4 + u)*256;
      const int c = idx / 49, qq = idx - c*49;
      *(float4*)&fms[c*224 + ((qq ^ (c & 7)) << 2)] = v[u];
    }
  }
  if (t < 64) {
    const int idx = t + 3072;
    const float4 v = src[idx];
    const int c = idx / 49, qq = idx - c*49;
    *(float4*)&fms[c*224 + ((qq ^ (c & 7)) << 2)] = v;
  }
  {
    const float4* wsrc = (const float4*)&ws[WS_WFM + (size_t)b*1664];
    float4 w0 = wsrc[t & 255];
    float4 w1 = (t < 160) ? wsrc[256 + t] : make_float4(0,0,0,0);
    *(float4*)&wfs[(t & 255)*4] = w0;
    if (t < 160) *(float4*)&wfs[(256 + t)*4] = w1;
  }
  __syncthreads();
  const int c = t & 63, hh = t >> 6;
  const int h0 = hh*2, h1 = h0+1;
  const int cx = (c & 7) << 2;
  const float* fr = &fms[c*224];
  const float* w0p = &wfs[h0*208];
  const float* w1p = &wfs[h1*208];
  float a0 = 0.f, a1 = 0.f;
#pragma unroll 7
  for (int p4 = 0; p4 < 49; ++p4) {
    const float4 f  = *(const float4*)&fr[((p4 << 2) ^ cx)];
    const float4 u0 = *(const float4*)&w0p[p4*4];
    const float4 u1 = *(const float4*)&w1p[p4*4];
    a0 += f.x*u0.x + f.y*u0.y + f.z*u0.z + f.w*u0.w;
    a1 += f.x*u1.x + f.y*u1.y + f.z*u1.z + f.w*u1.w;
  }
  ws[WS_S + ((size_t)h0*256 + b)*1024 + c0 + c] = a0;
  ws[WS_S + ((size_t)h1*256 + b)*1024 + c0 + c] = a1;
}

// ---------------- KB-POS: pos GEMM, accumulates into WS_S ----------------
__global__ __launch_bounds__(256) void kb_pos(float* __restrict__ ws)
{
  __shared__ float As[64 * 108];
  __shared__ float Bs[64 * 108];
  const int ct = blockIdx.x, rt = blockIdx.y, t = threadIdx.x;
  const int c0 = ct*64, r0 = rt*64;
  const int bq = t >> 4, cq = t & 15;
  float acc[4][4] = {};
  for (int sub = 0; sub < 2; ++sub) {
    const int k0 = sub * 104;
    __syncthreads();
    for (int idx = t; idx < 1664; idx += 256) {
      const int r = idx / 26, q = idx - r*26;
      const float4 av = *(const float4*)&ws[WS_WPOS + (size_t)(r0 + r)*208 + k0 + q*4];
      float* da = &As[r*108 + q*4];
      da[0]=av.x; da[1]=av.y; da[2]=av.z; da[3]=av.w;
      const float4 bv = *(const float4*)&ws[WS_POST + (size_t)(c0 + r)*208 + k0 + q*4];
      float* db = &Bs[r*108 + q*4];
      db[0]=bv.x; db[1]=bv.y; db[2]=bv.z; db[3]=bv.w;
    }
    __syncthreads();
    for (int k4 = 0; k4 < 26; ++k4) {
      float4 av[4], bw[4];
#pragma unroll
      for (int i = 0; i < 4; ++i) av[i] = *(const float4*)&As[(bq + 16*i)*108 + k4*4];
#pragma unroll
      for (int j = 0; j < 4; ++j) bw[j] = *(const float4*)&Bs[(cq + 16*j)*108 + k4*4];
#pragma unroll
      for (int i = 0; i < 4; ++i)
#pragma unroll
        for (int j = 0; j < 4; ++j)
          acc[i][j] += av[i].x*bw[j].x + av[i].y*bw[j].y + av[i].z*bw[j].z + av[i].w*bw[j].w;
    }
  }
#pragma unroll
  for (int i = 0; i < 4; ++i) {
    const int rIdx = r0 + bq + 16*i;
    const int b = rIdx >> 3, h = rIdx & 7;
    float* srow = &ws[WS_S + ((size_t)h*256 + b)*1024];
#pragma unroll
    for (int j = 0; j < 4; ++j) {
      const int c = c0 + cq + 16*j;
      srow[c] += acc[i][j];
    }
  }
}

// ---------------- KV: ov partials (per-head GEMM, k-split) ----------------
__global__ __launch_bounds__(256) void kv_ov(
    const float* __restrict__ wv, float* __restrict__ ws)
{
  const int kt = blockIdx.x, bt = blockIdx.y, h = blockIdx.z, t = threadIdx.x;
  __shared__ float At[64 * 65];
  __shared__ float Bt[64 * 65];
  const int b0 = bt*64, k0 = kt*128;
  const int bq = t >> 4, dq = t & 15;
  float acc[4][4] = {};
  for (int sub = 0; sub < 2; ++sub) {
    const int kk0 = k0 + sub*64;
    __syncthreads();
    for (int r = 0; r < 4; ++r) {
      const int idx = t + 256*r;
      const int bi = idx >> 4, c4 = idx & 15;
      const float4 v = *(const float4*)&ws[WS_S + ((size_t)h*256 + b0 + bi)*1024 + kk0 + c4*4];
      float* d1 = &At[bi*65 + c4*4];
      d1[0]=v.x; d1[1]=v.y; d1[2]=v.z; d1[3]=v.w;
      const float4 w = *(const float4*)&wv[(size_t)(h*64 + bi)*1024 + kk0 + c4*4];
      float* d2 = &Bt[bi*65 + c4*4];
      d2[0]=w.x; d2[1]=w.y; d2[2]=w.z; d2[3]=w.w;
    }
    __syncthreads();
    for (int kk = 0; kk < 64; ++kk) {
      float av[4], bw[4];
#pragma unroll
      for (int i = 0; i < 4; ++i) av[i] = At[(bq*4+i)*65 + kk];
#pragma unroll
      for (int j = 0; j < 4; ++j) bw[j] = Bt[(dq*4+j)*65 + kk];
#pragma unroll
      for (int i = 0; i < 4; ++i)
#pragma unroll
        for (int j = 0; j < 4; ++j) acc[i][j] += av[i]*bw[j];
    }
  }
#pragma unroll
  for (int i = 0; i < 4; ++i) {
    *(float4*)&ws[WS_OVP + ((size_t)kt*256 + b0 + bq*4 + i)*512 + h*64 + dq*4] =
        make_float4(acc[i][0], acc[i][1], acc[i][2], acc[i][3]);
  }
}

// ---------------- KOR: reduce ov partials + bv -> OV (256x512) ----------------
__global__ __launch_bounds__(256) void kor_ovred(
    const float* __restrict__ bv, float* __restrict__ ws)
{
  const int b = blockIdx.x, t = threadIdx.x;
  for (int j = t; j < 512; j += 256) {
    float s = bv[j];
    for (int kt = 0; kt < 8; ++kt)
      s += ws[WS_OVP + ((size_t)kt*256 + b)*512 + j];
    ws[WS_OV + (size_t)b*512 + j] = s;
  }
}

// ---------------- KO: out1 partials (GEMM vs wo, k-split) ----------------
__global__ __launch_bounds__(256) void ko_out(
    const float* __restrict__ wo, float* __restrict__ ws)
{
  const int kt2 = blockIdx.x, ct = blockIdx.y, bt = blockIdx.z, t = threadIdx.x;
  __shared__ float At[64 * 65];
  __shared__ float Bt[64 * 65];
  const int b0 = bt*64, c0 = ct*64, j0 = kt2*128;
  const int bq = t >> 4, cq = t & 15;
  float acc[4][4] = {};
  for (int sub = 0; sub < 2; ++sub) {
    const int jj0 = j0 + sub*64;
    __syncthreads();
    for (int r = 0; r < 4; ++r) {
      const int idx = t + 256*r;
      const int bi = idx >> 4, j4 = idx & 15;
      const float4 p = *(const float4*)&ws[WS_OV + (size_t)(b0 + bi)*512 + jj0 + j4*4];
      float* d1 = &At[bi*65 + j4*4];
      d1[0]=p.x; d1[1]=p.y; d1[2]=p.z; d1[3]=p.w;
      const float4 w = *(const float4*)&wo[(size_t)(c0 + bi)*512 + jj0 + j4*4];
      float* d2 = &Bt[bi*65 + j4*4];
      d2[0]=w.x; d2[1]=w.y; d2[2]=w.z; d2[3]=w.w;
    }
    __syncthreads();
    for (int jj = 0; jj < 64; ++jj) {
      float av[4], bw[4];
#pragma unroll
      for (int i = 0; i < 4; ++i) av[i] = At[(bq*4+i)*65 + jj];
#pragma unroll
      for (int j = 0; j < 4; ++j) bw[j] = Bt[(cq*4+j)*65 + jj];
#pragma unroll
      for (int i = 0; i < 4; ++i)
#pragma unroll
        for (int j = 0; j < 4; ++j) acc[i][j] += av[i]*bw[j];
    }
  }
#pragma unroll
  for (int i = 0; i < 4; ++i) {
    *(float4*)&ws[WS_O1P + ((size_t)kt2*256 + b0 + bq*4 + i)*1024 + c0 + cq*4] =
        make_float4(acc[i][0], acc[i][1], acc[i][2], acc[i][3]);
  }
}

// ---------------- KLN: residual + LayerNorm ----------------
__global__ __launch_bounds__(256) void kln_final(
    const float* __restrict__ bo, const float* __restrict__ ln_g,
    const float* __restrict__ ln_b, const float* __restrict__ ws,
    float* __restrict__ out)
{
  const int b = blockIdx.x, t = threadIdx.x;
  __shared__ float rs[256], rq[256];
  float m0r[8];
#pragma unroll
  for (int j = 0; j < 8; ++j) m0r[j] = ws[WS_M0 + (size_t)b*8 + j];
  float r[4];
  float sum = 0.f, sumsq = 0.f;
  for (int k = 0; k < 4; ++k) {
    const int c = t + 256*k;
    float o1 = bo[c];
    for (int kt2 = 0; kt2 < 4; ++kt2)
      o1 += ws[WS_O1P + ((size_t)kt2*256 + b)*1024 + c];
    const float* wc = &ws[WS_WC + c*8];
    float qv = ws[WS_BCQ + c];
#pragma unroll
    for (int j = 0; j < 8; ++j) qv += wc[j]*m0r[j];
    const float res = qv + o1;
    r[k] = res; sum += res; sumsq += res*res;
  }
  rs[t] = sum; rq[t] = sumsq;
  __syncthreads();
  for (int s2 = 128; s2 >= 1; s2 >>= 1) {
    if (t < s2) { rs[t] += rs[t+s2]; rq[t] += rq[t+s2]; }
    __syncthreads();
  }
  const float mu  = rs[0] * (1.f/1024.f);
  const float var = rq[0] * (1.f/1024.f) - mu*mu;
  const float inv = rsqrtf(var + 1e-5f);
  for (int k = 0; k < 4; ++k) {
    const int c = t + 256*k;
    out[(size_t)b*1024 + c] = (r[k] - mu)*inv*ln_g[c] + ln_b[c];
  }
}

// ---------------- launcher ----------------
extern "C" void kernel_launch(void* const* d_in, const int* in_sizes, int n_in,
                              void* d_out, int out_size, void* d_ws, size_t ws_size,
                              hipStream_t stream)
{
  const float* fm   = (const float*)d_in[0];
  const float* lmap = (const float*)d_in[1];
  const float* w1 = (const float*)d_in[2];  const float* b1 = (const float*)d_in[3];
  const float* w2 = (const float*)d_in[4];  const float* b2 = (const float*)d_in[5];
  const float* w3 = (const float*)d_in[6];  const float* b3 = (const float*)d_in[7];
  const float* w4 = (const float*)d_in[8];  const float* b4 = (const float*)d_in[9];
  const float* w5 = (const float*)d_in[10]; const float* b5 = (const float*)d_in[11];
  const float* wq = (const float*)d_in[12]; const float* bq = (const float*)d_in[13];
  const float* wk = (const float*)d_in[14]; const float* bk = (const float*)d_in[15];
  const float* wv = (const float*)d_in[16]; const float* bv = (const float*)d_in[17];
  const float* wo = (const float*)d_in[18]; const float* bo = (const float*)d_in[19];
  const float* ln_g = (const float*)d_in[20]; const float* ln_b = (const float*)d_in[21];
  const float* pos_kv = (const float*)d_in[22]; const float* pos_q = (const float*)d_in[23];
  float* ws  = (float*)d_ws;
  float* out = (float*)d_out;

  kp1a_chain_post<<<dim3(17), dim3(256), 0, stream>>>(w1,b1,w2,b2,w3,b3,w4,b4,pos_kv,ws);
  kp1b_w5fold<<<dim3(32), dim3(256), 0, stream>>>(w5,b5,pos_q,ws);
  kp2a_qproj<<<dim3(128), dim3(256), 0, stream>>>(wq,bq,ws);
  kp2b_gfold<<<dim3(4,8), dim3(256), 0, stream>>>(wk,bk,pos_kv,ws);
  ka_att<<<dim3(4,256), dim3(256), 0, stream>>>(fm,lmap,ws);
  ksm_softmax<<<dim3(256), dim3(256), 0, stream>>>(ws);
  kb_fm<<<dim3(16,256), dim3(256), 0, stream>>>(fm,ws);
  kb_pos<<<dim3(16,32), dim3(256), 0, stream>>>(ws);
  kv_ov<<<dim3(8,4,8), dim3(256), 0, stream>>>(wv,ws);
  kor_ovred<<<dim3(256), dim3(256), 0, stream>>>(bv,ws);
  ko_out<<<dim3(4,16,4), dim3(256), 0, stream>>>(wo,ws);
  kln_final<<<dim3(256), dim3(256), 0, stream>>>(bo,ln_g,ln_b,ws,out);
}